// Round 10
// baseline (274.264 us; speedup 1.0000x reference)
//
#include <hip/hip_runtime.h>

// GCNBlock: out = relu( D^-1/2 (A+I) D^-1/2 (x@W) + b )
// N=50000, E=800000, D=64, fp32.
// R10: fill_ell's random 2B scatter (44-57us, 7x line-rewrite) replaced by
// two-level counting sort: binify (edges -> 782 dst-bins, packed u32,
// stream-per-bin writes) + build_ell (per-bin LDS staging, coalesced ELL/fc
// dump, z-scaling folded in). No global memset in the replay path.

#define TPB 256
#define MAXDEG 64
#define OVFCAP 8192
#define NPB 64          // nodes per bin (dst >> 6)
#define BINCAP 1792     // edge capacity per bin (mean 1024, sigma ~32)

// ---- per-wave edge dtype detection --------------------------------------
// int64 little-endian with values <2^31 => every odd 32-bit word is 0.
__device__ __forceinline__ int edges_are_i32(const unsigned* __restrict__ w) {
    int lane = threadIdx.x & 63;
    unsigned v = w[1 + 2 * lane];
    return __ballot(v != 0u) != 0ull;
}

__device__ __forceinline__ unsigned short f2bf(float f) {  // RNE to bf16
    unsigned u = __float_as_uint(f);
    u += 0x7FFFu + ((u >> 16) & 1u);
    return (unsigned short)(u >> 16);
}
__device__ __forceinline__ float bf2f(unsigned short h) {
    return __uint_as_float(((unsigned)h) << 16);
}
__device__ __forceinline__ unsigned scale2(unsigned v, float dd) {  // 2 bf16
    unsigned lo = (unsigned)f2bf(dd * bf2f((unsigned short)(v & 0xFFFFu)));
    unsigned hi = (unsigned)f2bf(dd * bf2f((unsigned short)(v >> 16)));
    return lo | (hi << 16);
}

__device__ __forceinline__ void load4(const void* ei, int is32, long long base, int* v) {
    if (is32) {
        int4 a = *(const int4*)((const int*)ei + base);
        v[0] = a.x; v[1] = a.y; v[2] = a.z; v[3] = a.w;
    } else {
        longlong4 a = *(const longlong4*)((const long long*)ei + base);
        v[0] = (int)a.x; v[1] = (int)a.y; v[2] = (int)a.z; v[3] = (int)a.w;
    }
}

// ---- gemm: z0 = bf16(x @ W); also zeroes bincnt[0..nbins] (ovf incl.) ---
__global__ __launch_bounds__(256) void gemm_z0(const float* __restrict__ x,
                                               const float* __restrict__ W,
                                               unsigned short* __restrict__ z0,
                                               unsigned* __restrict__ bincnt,
                                               int nbins, int n) {
    const int gid = blockIdx.x * 256 + (int)threadIdx.x;
    if (gid <= nbins) bincnt[gid] = 0u;  // bincnt[nbins] is the ovf counter

    const int lane = threadIdx.x & 63;
    const int wv   = threadIdx.x >> 6;
    const int row0 = blockIdx.x * 16 + wv * 4;

    float wc[64];
#pragma unroll
    for (int k = 0; k < 64; ++k) wc[k] = W[k * 64 + lane];

#pragma unroll
    for (int r = 0; r < 4; ++r) {
        int row = row0 + r;
        if (row >= n) return;  // wave-uniform
        const float4* xr = (const float4*)(x + (long long)row * 64);
        float acc = 0.f;
#pragma unroll
        for (int k4 = 0; k4 < 16; ++k4) {
            float4 xv = xr[k4];
            acc = fmaf(xv.x, wc[4 * k4 + 0], acc);
            acc = fmaf(xv.y, wc[4 * k4 + 1], acc);
            acc = fmaf(xv.z, wc[4 * k4 + 2], acc);
            acc = fmaf(xv.w, wc[4 * k4 + 3], acc);
        }
        z0[(long long)row * 64 + lane] = f2bf(acc);
    }
}

// ---- binify: edges -> dst bins as packed (dst<<16)|src ------------------
__global__ __launch_bounds__(256) void binify(const void* __restrict__ ei,
                                              unsigned* __restrict__ bincnt,
                                              unsigned* __restrict__ binbuf,
                                              unsigned* __restrict__ ovf,
                                              int* __restrict__ ovfList, int E) {
    const int is32 = edges_are_i32((const unsigned*)ei);
    const long long t = (long long)blockIdx.x * 256 + threadIdx.x;
    const long long e0 = t * 4;
    if (e0 >= E) return;
    int s[4], d[4];
    const int m = (E - e0 >= 4) ? 4 : (int)(E - e0);
    if (m == 4) {
        load4(ei, is32, e0, s);
        load4(ei, is32, (long long)E + e0, d);
    } else {
        for (int k = 0; k < m; ++k) {
            if (is32) {
                s[k] = ((const int*)ei)[e0 + k];
                d[k] = ((const int*)ei)[(long long)E + e0 + k];
            } else {
                s[k] = (int)((const long long*)ei)[e0 + k];
                d[k] = (int)((const long long*)ei)[(long long)E + e0 + k];
            }
        }
    }
    unsigned pos[4];
#pragma unroll
    for (int k = 0; k < 4; ++k)
        if (k < m) pos[k] = atomicAdd(bincnt + ((unsigned)d[k] >> 6), 1u);
#pragma unroll
    for (int k = 0; k < 4; ++k) {
        if (k >= m) continue;
        if (pos[k] < BINCAP) {
            binbuf[((unsigned)d[k] >> 6) * BINCAP + pos[k]] =
                (unsigned)s[k] | ((unsigned)d[k] << 16);
        } else {  // bin overflow: ~0 probability; handled by gather's ovf scan
            unsigned p = atomicAdd(ovf, 1u);
            if (p < OVFCAP) { ovfList[2 * p] = s[k]; ovfList[2 * p + 1] = d[k]; }
        }
    }
}

// ---- build_ell: per-bin LDS staging -> coalesced ELL + fc + scaled z ----
__global__ __launch_bounds__(256) void build_ell(const unsigned* __restrict__ bincnt,
                                                 const unsigned* __restrict__ binbuf,
                                                 unsigned* __restrict__ fc,
                                                 unsigned short* __restrict__ ell,
                                                 unsigned* __restrict__ ovf,
                                                 int* __restrict__ ovfList,
                                                 unsigned short* __restrict__ z,
                                                 int n, int nbins) {
    __shared__ unsigned lcnt[NPB];
    __shared__ __align__(16) unsigned short lell[NPB * MAXDEG];  // 8 KB
    const int bin  = blockIdx.x;
    const int base = bin * NPB;
    const int t    = threadIdx.x;

    if (t < NPB) lcnt[t] = 0u;
    __syncthreads();

    unsigned cnt = bincnt[bin];
    if (cnt > BINCAP) cnt = BINCAP;
    const unsigned* bb = binbuf + (unsigned)bin * BINCAP;
    for (unsigned i = t; i < cnt; i += 256) {
        unsigned e  = bb[i];
        unsigned dst = e >> 16;
        unsigned dl  = dst - (unsigned)base;
        unsigned c = atomicAdd(&lcnt[dl], 1u);
        if (c < MAXDEG) {
            lell[dl * MAXDEG + c] = (unsigned short)(e & 0xFFFFu);
        } else {  // deg > 64: exact count kept in lcnt; extra edge via ovfList
            unsigned p = atomicAdd(ovf, 1u);
            if (p < OVFCAP) { ovfList[2 * p] = (int)(e & 0xFFFFu); ovfList[2 * p + 1] = (int)dst; }
        }
    }
    __syncthreads();

    const int maxrow = (n - base < NPB) ? (n - base) : NPB;
    if (t < NPB && t < maxrow) fc[base + t] = lcnt[t];

    // coalesced ELL dump: maxrow rows x 128B (8 uint4 per row)
    const uint4* lp = (const uint4*)lell;
    uint4* gp = (uint4*)(ell + (long long)base * MAXDEG);
    for (int i = t; i < maxrow * 8; i += 256) gp[i] = lp[i];

    // scale z rows in place: z[row] *= rsqrt(1 + deg)
    uint4* zp = (uint4*)(z + (long long)base * 64);
    for (int i = t; i < maxrow * 8; i += 256) {
        int row = i >> 3;
        float dd = rsqrtf(1.0f + (float)lcnt[row]);
        uint4 v = zp[i];
        v.x = scale2(v.x, dd); v.y = scale2(v.y, dd);
        v.z = scale2(v.z, dd); v.w = scale2(v.w, dd);
        zp[i] = v;
    }
}

// ---- gather: out = relu( dd * (z[node] + sum z[nbr]) + b ) --------------
__global__ __launch_bounds__(256) void gather_z(const unsigned short* __restrict__ ell,
                                                const unsigned* __restrict__ fc,
                                                const unsigned* __restrict__ ovf,
                                                const int* __restrict__ ovfList,
                                                const unsigned short* __restrict__ z,
                                                const float* __restrict__ b,
                                                float* __restrict__ out, int n) {
    const int node = blockIdx.x * 4 + ((int)threadIdx.x >> 6);
    const int lane = threadIdx.x & 63;
    if (node >= n) return;  // wave-uniform

    const unsigned deg = fc[node];
    const float dd = rsqrtf(1.0f + (float)deg);
    float acc = bf2f(z[(unsigned)node * 64 + lane]);  // self-loop term

    const uint4* prow = (const uint4*)(ell + (unsigned)node * MAXDEG);
    const unsigned m = deg < MAXDEG ? deg : MAXDEG;

    unsigned i = 0;
    for (; i + 8 <= m; i += 8) {
        uint4 rw = prow[i >> 3];
        unsigned s[8];
        s[0] = rw.x & 0xFFFFu; s[1] = rw.x >> 16;
        s[2] = rw.y & 0xFFFFu; s[3] = rw.y >> 16;
        s[4] = rw.z & 0xFFFFu; s[5] = rw.z >> 16;
        s[6] = rw.w & 0xFFFFu; s[7] = rw.w >> 16;
        float v[8];
#pragma unroll
        for (int k = 0; k < 8; ++k) v[k] = bf2f(z[s[k] * 64u + lane]);
#pragma unroll
        for (int k = 0; k < 8; ++k) acc += v[k];
    }
    for (; i < m; ++i) {
        unsigned s = ell[(unsigned)node * MAXDEG + i];
        acc += bf2f(z[s * 64u + lane]);
    }

    unsigned nov = *ovf;  // overflow edges: normally zero
    if (nov > 0) {
        nov = nov < OVFCAP ? nov : OVFCAP;
        for (unsigned j = 0; j < nov; ++j)
            if (ovfList[2 * j + 1] == node)
                acc += bf2f(z[(unsigned)ovfList[2 * j] * 64u + lane]);
    }

    out[(unsigned)node * 64 + lane] = fmaxf(fmaf(dd, acc, b[lane]), 0.f);
}

extern "C" void kernel_launch(void* const* d_in, const int* in_sizes, int n_in,
                              void* d_out, int out_size, void* d_ws, size_t ws_size,
                              hipStream_t stream) {
    const float* x  = (const float*)d_in[0];
    const void*  ei = d_in[1];
    const float* W  = (const float*)d_in[2];
    const float* b  = (const float*)d_in[3];
    float* out = (float*)d_out;

    const int n = in_sizes[0] / 64;   // 50000
    const int E = in_sizes[1] / 2;    // 800000
    const int nbins = (n + NPB - 1) / NPB;  // 782

    // ws: z[n*64] u16 | ell[n*64] u16 | fc[n] u32 | bincnt[nbins+1] u32
    //     | ovfList[2*OVFCAP] int | binbuf[nbins*BINCAP] u32  => ~18.7MB
    unsigned short* z       = (unsigned short*)d_ws;
    unsigned short* ell     = z + (long long)n * 64;
    unsigned*       fc      = (unsigned*)(ell + (long long)n * 64);
    unsigned*       bincnt  = fc + n;
    unsigned*       ovf     = bincnt + nbins;        // zeroed by gemm_z0
    int*            ovfList = (int*)(ovf + 1);
    unsigned*       binbuf  = (unsigned*)(ovfList + 2 * OVFCAP);

    gemm_z0<<<(n + 15) / 16, TPB, 0, stream>>>(x, W, z, bincnt, nbins, n);
    binify<<<(int)(((long long)E + 3) / 4 + TPB - 1) / TPB, TPB, 0, stream>>>(
        ei, bincnt, binbuf, ovf, ovfList, E);
    build_ell<<<nbins, TPB, 0, stream>>>(bincnt, binbuf, fc, ell, ovf, ovfList, z, n, nbins);
    gather_z<<<(n + 3) / 4, TPB, 0, stream>>>(ell, fc, ovf, ovfList, z, b, out, n);
}

// Round 11
// 93.484 us; speedup vs baseline: 2.9338x; 2.9338x over previous
//
#include <hip/hip_runtime.h>

// GCNBlock: out = relu( D^-1/2 (A+I) D^-1/2 (x@W) + b )
// N=50000, E=800000, D=64, fp32.
// R11: R10's binify died of 800K atomics on 782 counters (194us). Replace
// with atomic-free block-local bin sort: each 4096-edge block histograms/
// scans/scatters in LDS, dumps bin-sorted edges COALESCED to its own arena
// chunk + per-(bin,block) descriptors. build_ell stitches segments per bin
// (R10's proven LDS-ELL + coalesced dump + z-scale). No global scatter, no
// contended atomics anywhere.

#define TPB 256
#define MAXDEG 64
#define OVFCAP 8192
#define EPB 4096      // edges per binsort block
#define MAXBIN 1024   // supports n <= 65536
#define MAXBLK 256    // supports E <= 1M

// ---- per-wave edge dtype detection --------------------------------------
// int64 little-endian with values <2^31 => every odd 32-bit word is 0.
__device__ __forceinline__ int edges_are_i32(const unsigned* __restrict__ w) {
    int lane = threadIdx.x & 63;
    unsigned v = w[1 + 2 * lane];
    return __ballot(v != 0u) != 0ull;
}

__device__ __forceinline__ unsigned short f2bf(float f) {  // RNE to bf16
    unsigned u = __float_as_uint(f);
    u += 0x7FFFu + ((u >> 16) & 1u);
    return (unsigned short)(u >> 16);
}
__device__ __forceinline__ float bf2f(unsigned short h) {
    return __uint_as_float(((unsigned)h) << 16);
}
__device__ __forceinline__ unsigned scale2(unsigned v, float dd) {  // 2 bf16
    unsigned lo = (unsigned)f2bf(dd * bf2f((unsigned short)(v & 0xFFFFu)));
    unsigned hi = (unsigned)f2bf(dd * bf2f((unsigned short)(v >> 16)));
    return lo | (hi << 16);
}

__device__ __forceinline__ void load4(const void* ei, int is32, long long base, int* v) {
    if (is32) {
        int4 a = *(const int4*)((const int*)ei + base);
        v[0] = a.x; v[1] = a.y; v[2] = a.z; v[3] = a.w;
    } else {
        longlong4 a = *(const longlong4*)((const long long*)ei + base);
        v[0] = (int)a.x; v[1] = (int)a.y; v[2] = (int)a.z; v[3] = (int)a.w;
    }
}

// ---- gemm: z0 = bf16(x @ W); zeroes the ovf counter ---------------------
__global__ __launch_bounds__(256) void gemm_z0(const float* __restrict__ x,
                                               const float* __restrict__ W,
                                               unsigned short* __restrict__ z0,
                                               unsigned* __restrict__ ovf, int n) {
    if (blockIdx.x == 0 && threadIdx.x == 0) *ovf = 0u;

    const int lane = threadIdx.x & 63;
    const int wv   = threadIdx.x >> 6;
    const int row0 = blockIdx.x * 16 + wv * 4;

    float wc[64];
#pragma unroll
    for (int k = 0; k < 64; ++k) wc[k] = W[k * 64 + lane];

#pragma unroll
    for (int r = 0; r < 4; ++r) {
        int row = row0 + r;
        if (row >= n) return;  // wave-uniform
        const float4* xr = (const float4*)(x + (long long)row * 64);
        float acc = 0.f;
#pragma unroll
        for (int k4 = 0; k4 < 16; ++k4) {
            float4 xv = xr[k4];
            acc = fmaf(xv.x, wc[4 * k4 + 0], acc);
            acc = fmaf(xv.y, wc[4 * k4 + 1], acc);
            acc = fmaf(xv.z, wc[4 * k4 + 2], acc);
            acc = fmaf(xv.w, wc[4 * k4 + 3], acc);
        }
        z0[(long long)row * 64 + lane] = f2bf(acc);
    }
}

// ---- binsort: block-local LDS counting sort of 4096 edges by dst>>6 -----
// Arena chunk = the block's own edge range (no reservation atomics).
// Edge payload: (dst&63)<<16 | src (node ids < 65536).
__global__ __launch_bounds__(256) void binsort(const void* __restrict__ ei,
                                               unsigned* __restrict__ arena,
                                               uint2* __restrict__ desc,
                                               int E, int nbins, int nblocks) {
    __shared__ unsigned hist[MAXBIN];
    __shared__ unsigned bstart[MAXBIN];
    __shared__ unsigned cur[MAXBIN];
    __shared__ unsigned sorted[EPB];
    __shared__ unsigned partial[256];
    const int t   = threadIdx.x;
    const int blk = blockIdx.x;
    const long long base = (long long)blk * EPB;
    const int cnt = (int)((E - base < EPB) ? (E - base) : EPB);
    const int is32 = edges_are_i32((const unsigned*)ei);

    for (int i = t; i < nbins; i += 256) hist[i] = 0u;
    __syncthreads();

    unsigned pay[16];
    unsigned short bn[16];
#pragma unroll
    for (int r = 0; r < 4; ++r) {
        const int lo = r * 1024 + t * 4;  // local offset of this 4-pack
        if (lo + 4 <= cnt) {
            int s4[4], d4[4];
            load4(ei, is32, base + lo, s4);
            load4(ei, is32, (long long)E + base + lo, d4);
#pragma unroll
            for (int k = 0; k < 4; ++k) {
                pay[r * 4 + k] = ((unsigned)(d4[k] & 63) << 16) | (unsigned)s4[k];
                bn[r * 4 + k]  = (unsigned short)((unsigned)d4[k] >> 6);
                atomicAdd(&hist[bn[r * 4 + k]], 1u);
            }
        } else {
#pragma unroll
            for (int k = 0; k < 4; ++k) {
                int l = lo + k;
                if (l < cnt) {
                    int s_, d_;
                    if (is32) {
                        s_ = ((const int*)ei)[base + l];
                        d_ = ((const int*)ei)[(long long)E + base + l];
                    } else {
                        s_ = (int)((const long long*)ei)[base + l];
                        d_ = (int)((const long long*)ei)[(long long)E + base + l];
                    }
                    pay[r * 4 + k] = ((unsigned)(d_ & 63) << 16) | (unsigned)s_;
                    bn[r * 4 + k]  = (unsigned short)((unsigned)d_ >> 6);
                    atomicAdd(&hist[bn[r * 4 + k]], 1u);
                } else {
                    bn[r * 4 + k] = 0xFFFFu;  // invalid sentinel
                }
            }
        }
    }
    __syncthreads();

    // exclusive prefix over nbins (4 bins per thread + 256-wide scan)
    unsigned s0 = 0;
#pragma unroll
    for (int k = 0; k < 4; ++k) { int bq = t * 4 + k; if (bq < nbins) s0 += hist[bq]; }
    partial[t] = s0;
    __syncthreads();
    for (int o = 1; o < 256; o <<= 1) {
        unsigned v = (t >= o) ? partial[t - o] : 0u;
        __syncthreads();
        partial[t] += v;
        __syncthreads();
    }
    unsigned run = (t == 0) ? 0u : partial[t - 1];
#pragma unroll
    for (int k = 0; k < 4; ++k) {
        int bq = t * 4 + k;
        if (bq < nbins) { bstart[bq] = run; cur[bq] = run; run += hist[bq]; }
    }
    __syncthreads();

    // LDS scatter into bin order
#pragma unroll
    for (int i = 0; i < 16; ++i) {
        if (bn[i] != 0xFFFFu) {
            unsigned p = atomicAdd(&cur[bn[i]], 1u);
            sorted[p] = pay[i];
        }
    }
    __syncthreads();

    // coalesced arena dump + descriptors
    for (int i = t; i < cnt; i += 256) arena[base + i] = sorted[i];
    for (int bq = t; bq < nbins; bq += 256) {
        uint2 dd;
        dd.x = (unsigned)(base + bstart[bq]);
        dd.y = hist[bq];
        desc[(unsigned)bq * nblocks + blk] = dd;
    }
}

// ---- build_ell: per-bin segment stitch -> LDS ELL -> coalesced dump -----
// Also writes fc and scales z rows by rsqrt(1+deg) in place.
__global__ __launch_bounds__(256) void build_ell(const uint2* __restrict__ desc,
                                                 const unsigned* __restrict__ arena,
                                                 unsigned* __restrict__ fc,
                                                 unsigned short* __restrict__ ell,
                                                 unsigned* __restrict__ ovf,
                                                 int* __restrict__ ovfList,
                                                 unsigned short* __restrict__ z,
                                                 int n, int nblocks) {
    __shared__ unsigned segstart[MAXBLK];
    __shared__ unsigned segpre[MAXBLK];
    __shared__ unsigned pre[256];
    __shared__ unsigned lcnt[MAXDEG];
    __shared__ __align__(16) unsigned short lell[MAXDEG * MAXDEG];  // 8 KB
    const int t   = threadIdx.x;
    const int bin = blockIdx.x;
    const int base = bin * MAXDEG;

    if (t < MAXDEG) lcnt[t] = 0u;

    unsigned len = 0;
    if (t < nblocks) {
        uint2 dd = desc[(unsigned)bin * nblocks + t];
        segstart[t] = dd.x;
        len = dd.y;
    }
    pre[t] = len;
    __syncthreads();
    for (int o = 1; o < 256; o <<= 1) {
        unsigned v = (t >= o) ? pre[t - o] : 0u;
        __syncthreads();
        pre[t] += v;
        __syncthreads();
    }
    const unsigned total = pre[255];
    segpre[t < nblocks ? t : 0] = 0;  // placate compiler; real write below
    if (t < nblocks) segpre[t] = pre[t] - len;  // exclusive prefix
    __syncthreads();

    for (unsigned j = t; j < total; j += 256) {
        // largest k with segpre[k] <= j (segpre nondecreasing)
        int lo = 0, hi = nblocks - 1;
        while (lo < hi) {
            int mid = (lo + hi + 1) >> 1;
            if (segpre[mid] <= j) lo = mid; else hi = mid - 1;
        }
        unsigned e  = arena[segstart[lo] + (j - segpre[lo])];
        unsigned dl = e >> 16;
        unsigned c  = atomicAdd(&lcnt[dl], 1u);
        if (c < MAXDEG) {
            lell[dl * MAXDEG + c] = (unsigned short)(e & 0xFFFFu);
        } else {  // deg > 64: exact deg kept in lcnt; extra edge via ovfList
            unsigned p = atomicAdd(ovf, 1u);
            if (p < OVFCAP) {
                ovfList[2 * p]     = (int)(e & 0xFFFFu);
                ovfList[2 * p + 1] = base + (int)dl;
            }
        }
    }
    __syncthreads();

    const int maxrow = (n - base < MAXDEG) ? (n - base) : MAXDEG;
    if (t < maxrow) fc[base + t] = lcnt[t];

    // coalesced ELL dump: maxrow rows x 128B (8 uint4 per row)
    const uint4* lp = (const uint4*)lell;
    uint4* gp = (uint4*)(ell + (long long)base * MAXDEG);
    for (int i = t; i < maxrow * 8; i += 256) gp[i] = lp[i];

    // scale z rows in place: z[row] *= rsqrt(1 + deg)
    uint4* zp = (uint4*)(z + (long long)base * 64);
    for (int i = t; i < maxrow * 8; i += 256) {
        int row = i >> 3;
        float dd = rsqrtf(1.0f + (float)lcnt[row]);
        uint4 v = zp[i];
        v.x = scale2(v.x, dd); v.y = scale2(v.y, dd);
        v.z = scale2(v.z, dd); v.w = scale2(v.w, dd);
        zp[i] = v;
    }
}

// ---- gather: out = relu( dd * (z[node] + sum z[nbr]) + b ) --------------
__global__ __launch_bounds__(256) void gather_z(const unsigned short* __restrict__ ell,
                                                const unsigned* __restrict__ fc,
                                                const unsigned* __restrict__ ovf,
                                                const int* __restrict__ ovfList,
                                                const unsigned short* __restrict__ z,
                                                const float* __restrict__ b,
                                                float* __restrict__ out, int n) {
    const int node = blockIdx.x * 4 + ((int)threadIdx.x >> 6);
    const int lane = threadIdx.x & 63;
    if (node >= n) return;  // wave-uniform

    const unsigned deg = fc[node];
    const float dd = rsqrtf(1.0f + (float)deg);
    float acc = bf2f(z[(unsigned)node * 64 + lane]);  // self-loop term

    const uint4* prow = (const uint4*)(ell + (unsigned)node * MAXDEG);
    const unsigned m = deg < MAXDEG ? deg : MAXDEG;

    unsigned i = 0;
    for (; i + 8 <= m; i += 8) {
        uint4 rw = prow[i >> 3];
        unsigned s[8];
        s[0] = rw.x & 0xFFFFu; s[1] = rw.x >> 16;
        s[2] = rw.y & 0xFFFFu; s[3] = rw.y >> 16;
        s[4] = rw.z & 0xFFFFu; s[5] = rw.z >> 16;
        s[6] = rw.w & 0xFFFFu; s[7] = rw.w >> 16;
        float v[8];
#pragma unroll
        for (int k = 0; k < 8; ++k) v[k] = bf2f(z[s[k] * 64u + lane]);
#pragma unroll
        for (int k = 0; k < 8; ++k) acc += v[k];
    }
    for (; i < m; ++i) {
        unsigned s = ell[(unsigned)node * MAXDEG + i];
        acc += bf2f(z[s * 64u + lane]);
    }

    unsigned nov = *ovf;  // overflow edges: normally zero
    if (nov > 0) {
        nov = nov < OVFCAP ? nov : OVFCAP;
        for (unsigned j = 0; j < nov; ++j)
            if (ovfList[2 * j + 1] == node)
                acc += bf2f(z[(unsigned)ovfList[2 * j] * 64u + lane]);
    }

    out[(unsigned)node * 64 + lane] = fmaxf(fmaf(dd, acc, b[lane]), 0.f);
}

extern "C" void kernel_launch(void* const* d_in, const int* in_sizes, int n_in,
                              void* d_out, int out_size, void* d_ws, size_t ws_size,
                              hipStream_t stream) {
    const float* x  = (const float*)d_in[0];
    const void*  ei = d_in[1];
    const float* W  = (const float*)d_in[2];
    const float* b  = (const float*)d_in[3];
    float* out = (float*)d_out;

    const int n = in_sizes[0] / 64;   // 50000
    const int E = in_sizes[1] / 2;    // 800000
    const int nbins   = (n + MAXDEG - 1) / MAXDEG;  // 782
    const int nblocks = (E + EPB - 1) / EPB;        // 196

    // ws: z[n*64] u16 (6.4M) | ell[n*64] u16 (6.4M) | fc[n] u32 (0.2M) |
    //     ovf u32 | ovfList[2*OVFCAP] | arena[E] u32 (3.2M) |
    //     desc[nbins*nblocks] uint2 (1.23M)  => ~17.5MB (< proven 19.46MB)
    unsigned short* z       = (unsigned short*)d_ws;
    unsigned short* ell     = z + (long long)n * 64;
    unsigned*       fc      = (unsigned*)(ell + (long long)n * 64);
    unsigned*       ovf     = fc + n;
    int*            ovfList = (int*)(ovf + 1);
    unsigned*       arena   = (unsigned*)(ovfList + 2 * OVFCAP);
    uint2*          desc    = (uint2*)(arena + E);

    gemm_z0<<<(n + 15) / 16, TPB, 0, stream>>>(x, W, z, ovf, n);
    binsort<<<nblocks, TPB, 0, stream>>>(ei, arena, desc, E, nbins, nblocks);
    build_ell<<<nbins, TPB, 0, stream>>>(desc, arena, fc, ell, ovf, ovfList, z, n, nblocks);
    gather_z<<<(n + 3) / 4, TPB, 0, stream>>>(ell, fc, ovf, ovfList, z, b, out, n);
}

// Round 12
// 91.677 us; speedup vs baseline: 2.9916x; 1.0197x over previous
//
#include <hip/hip_runtime.h>

// GCNBlock: out = relu( D^-1/2 (A+I) D^-1/2 (x@W) + b )
// N=50000, E=800000, D=64, fp32.
// R12: binsort TPB 256->512 (196 blocks were 0.77/CU with a 4-wave critical
// path); desc layout transposed to desc[blk*nbins+bin] so binsort's
// descriptor dump is contiguous per block (was 153K scattered 8B RMW stores,
// the same pathology that killed fill_ell). build_ell reads desc strided
// (cached, no RMW). Everything else frozen from R11 (93.5us).

#define TPB 256
#define STPB 512      // binsort block size
#define MAXDEG 64
#define OVFCAP 8192
#define EPB 4096      // edges per binsort block
#define MAXBIN 1024   // supports n <= 65536
#define MAXBLK 256    // supports E <= 1M

// ---- per-wave edge dtype detection --------------------------------------
// int64 little-endian with values <2^31 => every odd 32-bit word is 0.
__device__ __forceinline__ int edges_are_i32(const unsigned* __restrict__ w) {
    int lane = threadIdx.x & 63;
    unsigned v = w[1 + 2 * lane];
    return __ballot(v != 0u) != 0ull;
}

__device__ __forceinline__ unsigned short f2bf(float f) {  // RNE to bf16
    unsigned u = __float_as_uint(f);
    u += 0x7FFFu + ((u >> 16) & 1u);
    return (unsigned short)(u >> 16);
}
__device__ __forceinline__ float bf2f(unsigned short h) {
    return __uint_as_float(((unsigned)h) << 16);
}
__device__ __forceinline__ unsigned scale2(unsigned v, float dd) {  // 2 bf16
    unsigned lo = (unsigned)f2bf(dd * bf2f((unsigned short)(v & 0xFFFFu)));
    unsigned hi = (unsigned)f2bf(dd * bf2f((unsigned short)(v >> 16)));
    return lo | (hi << 16);
}

__device__ __forceinline__ void load4(const void* ei, int is32, long long base, int* v) {
    if (is32) {
        int4 a = *(const int4*)((const int*)ei + base);
        v[0] = a.x; v[1] = a.y; v[2] = a.z; v[3] = a.w;
    } else {
        longlong4 a = *(const longlong4*)((const long long*)ei + base);
        v[0] = (int)a.x; v[1] = (int)a.y; v[2] = (int)a.z; v[3] = (int)a.w;
    }
}

// ---- gemm: z0 = bf16(x @ W); zeroes the ovf counter ---------------------
__global__ __launch_bounds__(256) void gemm_z0(const float* __restrict__ x,
                                               const float* __restrict__ W,
                                               unsigned short* __restrict__ z0,
                                               unsigned* __restrict__ ovf, int n) {
    if (blockIdx.x == 0 && threadIdx.x == 0) *ovf = 0u;

    const int lane = threadIdx.x & 63;
    const int wv   = threadIdx.x >> 6;
    const int row0 = blockIdx.x * 16 + wv * 4;

    float wc[64];
#pragma unroll
    for (int k = 0; k < 64; ++k) wc[k] = W[k * 64 + lane];

#pragma unroll
    for (int r = 0; r < 4; ++r) {
        int row = row0 + r;
        if (row >= n) return;  // wave-uniform
        const float4* xr = (const float4*)(x + (long long)row * 64);
        float acc = 0.f;
#pragma unroll
        for (int k4 = 0; k4 < 16; ++k4) {
            float4 xv = xr[k4];
            acc = fmaf(xv.x, wc[4 * k4 + 0], acc);
            acc = fmaf(xv.y, wc[4 * k4 + 1], acc);
            acc = fmaf(xv.z, wc[4 * k4 + 2], acc);
            acc = fmaf(xv.w, wc[4 * k4 + 3], acc);
        }
        z0[(long long)row * 64 + lane] = f2bf(acc);
    }
}

// ---- binsort: block-local LDS counting sort of 4096 edges by dst>>6 -----
// 512 threads, 8 edges/thread. Arena chunk = block's own range (no global
// atomics). desc layout: desc[blk*nbins+bin] -> contiguous dump per block.
__global__ __launch_bounds__(512) void binsort(const void* __restrict__ ei,
                                               unsigned* __restrict__ arena,
                                               uint2* __restrict__ desc,
                                               int E, int nbins, int nblocks) {
    __shared__ unsigned hist[MAXBIN];
    __shared__ unsigned bstart[MAXBIN];
    __shared__ unsigned cur[MAXBIN];
    __shared__ unsigned sorted[EPB];
    __shared__ unsigned partial[STPB];
    const int t   = threadIdx.x;
    const int blk = blockIdx.x;
    const long long base = (long long)blk * EPB;
    const int cnt = (int)((E - base < EPB) ? (E - base) : EPB);
    const int is32 = edges_are_i32((const unsigned*)ei);

    for (int i = t; i < nbins; i += STPB) hist[i] = 0u;
    __syncthreads();

    unsigned pay[8];
    unsigned short bn[8];
#pragma unroll
    for (int r = 0; r < 2; ++r) {
        const int lo = r * (STPB * 4) + t * 4;  // local offset of this 4-pack
        if (lo + 4 <= cnt) {
            int s4[4], d4[4];
            load4(ei, is32, base + lo, s4);
            load4(ei, is32, (long long)E + base + lo, d4);
#pragma unroll
            for (int k = 0; k < 4; ++k) {
                pay[r * 4 + k] = ((unsigned)(d4[k] & 63) << 16) | (unsigned)s4[k];
                bn[r * 4 + k]  = (unsigned short)((unsigned)d4[k] >> 6);
                atomicAdd(&hist[bn[r * 4 + k]], 1u);
            }
        } else {
#pragma unroll
            for (int k = 0; k < 4; ++k) {
                int l = lo + k;
                if (l < cnt) {
                    int s_, d_;
                    if (is32) {
                        s_ = ((const int*)ei)[base + l];
                        d_ = ((const int*)ei)[(long long)E + base + l];
                    } else {
                        s_ = (int)((const long long*)ei)[base + l];
                        d_ = (int)((const long long*)ei)[(long long)E + base + l];
                    }
                    pay[r * 4 + k] = ((unsigned)(d_ & 63) << 16) | (unsigned)s_;
                    bn[r * 4 + k]  = (unsigned short)((unsigned)d_ >> 6);
                    atomicAdd(&hist[bn[r * 4 + k]], 1u);
                } else {
                    bn[r * 4 + k] = 0xFFFFu;  // invalid sentinel
                }
            }
        }
    }
    __syncthreads();

    // exclusive prefix over nbins (2 bins per thread + 512-wide scan)
    unsigned s0 = 0;
#pragma unroll
    for (int k = 0; k < 2; ++k) { int bq = t * 2 + k; if (bq < nbins) s0 += hist[bq]; }
    partial[t] = s0;
    __syncthreads();
    for (int o = 1; o < STPB; o <<= 1) {
        unsigned v = (t >= o) ? partial[t - o] : 0u;
        __syncthreads();
        partial[t] += v;
        __syncthreads();
    }
    unsigned run = (t == 0) ? 0u : partial[t - 1];
#pragma unroll
    for (int k = 0; k < 2; ++k) {
        int bq = t * 2 + k;
        if (bq < nbins) { bstart[bq] = run; cur[bq] = run; run += hist[bq]; }
    }
    __syncthreads();

    // LDS scatter into bin order
#pragma unroll
    for (int i = 0; i < 8; ++i) {
        if (bn[i] != 0xFFFFu) {
            unsigned p = atomicAdd(&cur[bn[i]], 1u);
            sorted[p] = pay[i];
        }
    }
    __syncthreads();

    // coalesced arena dump + contiguous descriptor dump
    for (int i = t; i < cnt; i += STPB) arena[base + i] = sorted[i];
    for (int bq = t; bq < nbins; bq += STPB) {
        uint2 dd;
        dd.x = (unsigned)(base + bstart[bq]);
        dd.y = hist[bq];
        desc[(long long)blk * nbins + bq] = dd;
    }
}

// ---- build_ell: per-bin segment stitch -> LDS ELL -> coalesced dump -----
// Also writes fc and scales z rows by rsqrt(1+deg) in place.
__global__ __launch_bounds__(256) void build_ell(const uint2* __restrict__ desc,
                                                 const unsigned* __restrict__ arena,
                                                 unsigned* __restrict__ fc,
                                                 unsigned short* __restrict__ ell,
                                                 unsigned* __restrict__ ovf,
                                                 int* __restrict__ ovfList,
                                                 unsigned short* __restrict__ z,
                                                 int n, int nbins, int nblocks) {
    __shared__ unsigned segstart[MAXBLK];
    __shared__ unsigned segpre[MAXBLK];
    __shared__ unsigned pre[256];
    __shared__ unsigned lcnt[MAXDEG];
    __shared__ __align__(16) unsigned short lell[MAXDEG * MAXDEG];  // 8 KB
    const int t   = threadIdx.x;
    const int bin = blockIdx.x;
    const int base = bin * MAXDEG;

    if (t < MAXDEG) lcnt[t] = 0u;

    unsigned len = 0;
    if (t < nblocks) {
        uint2 dd = desc[(long long)t * nbins + bin];  // strided read (cached)
        segstart[t] = dd.x;
        len = dd.y;
    }
    pre[t] = len;
    __syncthreads();
    for (int o = 1; o < 256; o <<= 1) {
        unsigned v = (t >= o) ? pre[t - o] : 0u;
        __syncthreads();
        pre[t] += v;
        __syncthreads();
    }
    const unsigned total = pre[255];
    if (t < nblocks) segpre[t] = pre[t] - len;  // exclusive prefix
    __syncthreads();

    for (unsigned j = t; j < total; j += 256) {
        // largest k with segpre[k] <= j (segpre nondecreasing)
        int lo = 0, hi = nblocks - 1;
        while (lo < hi) {
            int mid = (lo + hi + 1) >> 1;
            if (segpre[mid] <= j) lo = mid; else hi = mid - 1;
        }
        unsigned e  = arena[segstart[lo] + (j - segpre[lo])];
        unsigned dl = e >> 16;
        unsigned c  = atomicAdd(&lcnt[dl], 1u);
        if (c < MAXDEG) {
            lell[dl * MAXDEG + c] = (unsigned short)(e & 0xFFFFu);
        } else {  // deg > 64: exact deg kept in lcnt; extra edge via ovfList
            unsigned p = atomicAdd(ovf, 1u);
            if (p < OVFCAP) {
                ovfList[2 * p]     = (int)(e & 0xFFFFu);
                ovfList[2 * p + 1] = base + (int)dl;
            }
        }
    }
    __syncthreads();

    const int maxrow = (n - base < MAXDEG) ? (n - base) : MAXDEG;
    if (t < maxrow) fc[base + t] = lcnt[t];

    // coalesced ELL dump: maxrow rows x 128B (8 uint4 per row)
    const uint4* lp = (const uint4*)lell;
    uint4* gp = (uint4*)(ell + (long long)base * MAXDEG);
    for (int i = t; i < maxrow * 8; i += 256) gp[i] = lp[i];

    // scale z rows in place: z[row] *= rsqrt(1 + deg)
    uint4* zp = (uint4*)(z + (long long)base * 64);
    for (int i = t; i < maxrow * 8; i += 256) {
        int row = i >> 3;
        float dd = rsqrtf(1.0f + (float)lcnt[row]);
        uint4 v = zp[i];
        v.x = scale2(v.x, dd); v.y = scale2(v.y, dd);
        v.z = scale2(v.z, dd); v.w = scale2(v.w, dd);
        zp[i] = v;
    }
}

// ---- gather: out = relu( dd * (z[node] + sum z[nbr]) + b ) --------------
__global__ __launch_bounds__(256) void gather_z(const unsigned short* __restrict__ ell,
                                                const unsigned* __restrict__ fc,
                                                const unsigned* __restrict__ ovf,
                                                const int* __restrict__ ovfList,
                                                const unsigned short* __restrict__ z,
                                                const float* __restrict__ b,
                                                float* __restrict__ out, int n) {
    const int node = blockIdx.x * 4 + ((int)threadIdx.x >> 6);
    const int lane = threadIdx.x & 63;
    if (node >= n) return;  // wave-uniform

    const unsigned deg = fc[node];
    const float dd = rsqrtf(1.0f + (float)deg);
    float acc = bf2f(z[(unsigned)node * 64 + lane]);  // self-loop term

    const uint4* prow = (const uint4*)(ell + (unsigned)node * MAXDEG);
    const unsigned m = deg < MAXDEG ? deg : MAXDEG;

    unsigned i = 0;
    for (; i + 8 <= m; i += 8) {
        uint4 rw = prow[i >> 3];
        unsigned s[8];
        s[0] = rw.x & 0xFFFFu; s[1] = rw.x >> 16;
        s[2] = rw.y & 0xFFFFu; s[3] = rw.y >> 16;
        s[4] = rw.z & 0xFFFFu; s[5] = rw.z >> 16;
        s[6] = rw.w & 0xFFFFu; s[7] = rw.w >> 16;
        float v[8];
#pragma unroll
        for (int k = 0; k < 8; ++k) v[k] = bf2f(z[s[k] * 64u + lane]);
#pragma unroll
        for (int k = 0; k < 8; ++k) acc += v[k];
    }
    for (; i < m; ++i) {
        unsigned s = ell[(unsigned)node * MAXDEG + i];
        acc += bf2f(z[s * 64u + lane]);
    }

    unsigned nov = *ovf;  // overflow edges: normally zero
    if (nov > 0) {
        nov = nov < OVFCAP ? nov : OVFCAP;
        for (unsigned j = 0; j < nov; ++j)
            if (ovfList[2 * j + 1] == node)
                acc += bf2f(z[(unsigned)ovfList[2 * j] * 64u + lane]);
    }

    out[(unsigned)node * 64 + lane] = fmaxf(fmaf(dd, acc, b[lane]), 0.f);
}

extern "C" void kernel_launch(void* const* d_in, const int* in_sizes, int n_in,
                              void* d_out, int out_size, void* d_ws, size_t ws_size,
                              hipStream_t stream) {
    const float* x  = (const float*)d_in[0];
    const void*  ei = d_in[1];
    const float* W  = (const float*)d_in[2];
    const float* b  = (const float*)d_in[3];
    float* out = (float*)d_out;

    const int n = in_sizes[0] / 64;   // 50000
    const int E = in_sizes[1] / 2;    // 800000
    const int nbins   = (n + MAXDEG - 1) / MAXDEG;  // 782
    const int nblocks = (E + EPB - 1) / EPB;        // 196

    // ws: z[n*64] u16 (6.4M) | ell[n*64] u16 (6.4M) | fc[n] u32 (0.2M) |
    //     ovf u32 | ovfList[2*OVFCAP] | arena[E] u32 (3.2M) |
    //     desc[nblocks*nbins] uint2 (1.23M)  => ~17.5MB (< proven 19.46MB)
    unsigned short* z       = (unsigned short*)d_ws;
    unsigned short* ell     = z + (long long)n * 64;
    unsigned*       fc      = (unsigned*)(ell + (long long)n * 64);
    unsigned*       ovf     = fc + n;
    int*            ovfList = (int*)(ovf + 1);
    unsigned*       arena   = (unsigned*)(ovfList + 2 * OVFCAP);
    uint2*          desc    = (uint2*)(arena + E);

    gemm_z0<<<(n + 15) / 16, TPB, 0, stream>>>(x, W, z, ovf, n);
    binsort<<<nblocks, STPB, 0, stream>>>(ei, arena, desc, E, nbins, nblocks);
    build_ell<<<nbins, TPB, 0, stream>>>(desc, arena, fc, ell, ovf, ovfList, z,
                                         n, nbins, nblocks);
    gather_z<<<(n + 3) / 4, TPB, 0, stream>>>(ell, fc, ovf, ovfList, z, b, out, n);
}

// Round 13
// 90.481 us; speedup vs baseline: 3.0312x; 1.0132x over previous
//
#include <hip/hip_runtime.h>

// GCNBlock: out = relu( D^-1/2 (A+I) D^-1/2 (x@W) + b )
// N=50000, E=800000, D=64, fp32.
// R13: R12 profile exposed gemm_z0 = 41.5us @ VGPR=48 — the "W in 64 VGPRs"
// scheme NEVER existed (compiler re-read W from L1 per row, latency-bound).
// Rewrite: W staged in LDS (16KB, natural layout, bank-conflict-free b32
// reads), wave owns 8 rows, k-outer loop amortizes W reads over rows ->
// VALU-bound ~7us at ~32 VGPR. Binsort/build_ell/gather frozen from R12.

#define TPB 256
#define STPB 512      // binsort block size
#define MAXDEG 64
#define OVFCAP 8192
#define EPB 4096      // edges per binsort block
#define MAXBIN 1024   // supports n <= 65536
#define MAXBLK 256    // supports E <= 1M

// ---- per-wave edge dtype detection --------------------------------------
// int64 little-endian with values <2^31 => every odd 32-bit word is 0.
__device__ __forceinline__ int edges_are_i32(const unsigned* __restrict__ w) {
    int lane = threadIdx.x & 63;
    unsigned v = w[1 + 2 * lane];
    return __ballot(v != 0u) != 0ull;
}

__device__ __forceinline__ unsigned short f2bf(float f) {  // RNE to bf16
    unsigned u = __float_as_uint(f);
    u += 0x7FFFu + ((u >> 16) & 1u);
    return (unsigned short)(u >> 16);
}
__device__ __forceinline__ float bf2f(unsigned short h) {
    return __uint_as_float(((unsigned)h) << 16);
}
__device__ __forceinline__ unsigned scale2(unsigned v, float dd) {  // 2 bf16
    unsigned lo = (unsigned)f2bf(dd * bf2f((unsigned short)(v & 0xFFFFu)));
    unsigned hi = (unsigned)f2bf(dd * bf2f((unsigned short)(v >> 16)));
    return lo | (hi << 16);
}

__device__ __forceinline__ void load4(const void* ei, int is32, long long base, int* v) {
    if (is32) {
        int4 a = *(const int4*)((const int*)ei + base);
        v[0] = a.x; v[1] = a.y; v[2] = a.z; v[3] = a.w;
    } else {
        longlong4 a = *(const longlong4*)((const long long*)ei + base);
        v[0] = (int)a.x; v[1] = (int)a.y; v[2] = (int)a.z; v[3] = (int)a.w;
    }
}

// ---- gemm: z0 = bf16(x @ W) via LDS-staged W; zeroes the ovf counter ----
// Lane = output column. Wave owns 8 rows. k-outer: 4 W values from LDS
// (bank-conflict-free: lane c -> bank c%32, 2-way alias = free), 8
// wave-uniform float4 x loads, 32 FMAs. ~32 VGPR, VALU-bound.
__global__ __launch_bounds__(256) void gemm_z0(const float* __restrict__ x,
                                               const float* __restrict__ W,
                                               unsigned short* __restrict__ z0,
                                               unsigned* __restrict__ ovf, int n) {
    if (blockIdx.x == 0 && threadIdx.x == 0) *ovf = 0u;

    __shared__ float lw[4096];  // W[k*64+c], natural layout, 16 KB
    const int t = threadIdx.x;
#pragma unroll
    for (int i = 0; i < 16; ++i) lw[i * 256 + t] = W[i * 256 + t];
    __syncthreads();

    const int lane = t & 63;
    const int wv   = t >> 6;
    const int row0 = blockIdx.x * 32 + wv * 8;
    if (row0 >= n) return;  // wave-uniform
    const int nr = (n - row0 >= 8) ? 8 : (n - row0);

    float acc[8] = {0.f, 0.f, 0.f, 0.f, 0.f, 0.f, 0.f, 0.f};
#pragma unroll
    for (int k0 = 0; k0 < 16; ++k0) {
        const float w0 = lw[(4 * k0 + 0) * 64 + lane];
        const float w1 = lw[(4 * k0 + 1) * 64 + lane];
        const float w2 = lw[(4 * k0 + 2) * 64 + lane];
        const float w3 = lw[(4 * k0 + 3) * 64 + lane];
#pragma unroll
        for (int r = 0; r < 8; ++r) {
            if (r < nr) {
                float4 xv = *(const float4*)(x + (long long)(row0 + r) * 64 + 4 * k0);
                acc[r] = fmaf(xv.w, w3, fmaf(xv.z, w2, fmaf(xv.y, w1,
                         fmaf(xv.x, w0, acc[r]))));
            }
        }
    }
#pragma unroll
    for (int r = 0; r < 8; ++r)
        if (r < nr) z0[(long long)(row0 + r) * 64 + lane] = f2bf(acc[r]);
}

// ---- binsort: block-local LDS counting sort of 4096 edges by dst>>6 -----
// 512 threads, 8 edges/thread. Arena chunk = block's own range (no global
// atomics). desc layout: desc[blk*nbins+bin] -> contiguous dump per block.
__global__ __launch_bounds__(512) void binsort(const void* __restrict__ ei,
                                               unsigned* __restrict__ arena,
                                               uint2* __restrict__ desc,
                                               int E, int nbins, int nblocks) {
    __shared__ unsigned hist[MAXBIN];
    __shared__ unsigned bstart[MAXBIN];
    __shared__ unsigned cur[MAXBIN];
    __shared__ unsigned sorted[EPB];
    __shared__ unsigned partial[STPB];
    const int t   = threadIdx.x;
    const int blk = blockIdx.x;
    const long long base = (long long)blk * EPB;
    const int cnt = (int)((E - base < EPB) ? (E - base) : EPB);
    const int is32 = edges_are_i32((const unsigned*)ei);

    for (int i = t; i < nbins; i += STPB) hist[i] = 0u;
    __syncthreads();

    unsigned pay[8];
    unsigned short bn[8];
#pragma unroll
    for (int r = 0; r < 2; ++r) {
        const int lo = r * (STPB * 4) + t * 4;  // local offset of this 4-pack
        if (lo + 4 <= cnt) {
            int s4[4], d4[4];
            load4(ei, is32, base + lo, s4);
            load4(ei, is32, (long long)E + base + lo, d4);
#pragma unroll
            for (int k = 0; k < 4; ++k) {
                pay[r * 4 + k] = ((unsigned)(d4[k] & 63) << 16) | (unsigned)s4[k];
                bn[r * 4 + k]  = (unsigned short)((unsigned)d4[k] >> 6);
                atomicAdd(&hist[bn[r * 4 + k]], 1u);
            }
        } else {
#pragma unroll
            for (int k = 0; k < 4; ++k) {
                int l = lo + k;
                if (l < cnt) {
                    int s_, d_;
                    if (is32) {
                        s_ = ((const int*)ei)[base + l];
                        d_ = ((const int*)ei)[(long long)E + base + l];
                    } else {
                        s_ = (int)((const long long*)ei)[base + l];
                        d_ = (int)((const long long*)ei)[(long long)E + base + l];
                    }
                    pay[r * 4 + k] = ((unsigned)(d_ & 63) << 16) | (unsigned)s_;
                    bn[r * 4 + k]  = (unsigned short)((unsigned)d_ >> 6);
                    atomicAdd(&hist[bn[r * 4 + k]], 1u);
                } else {
                    bn[r * 4 + k] = 0xFFFFu;  // invalid sentinel
                }
            }
        }
    }
    __syncthreads();

    // exclusive prefix over nbins (2 bins per thread + 512-wide scan)
    unsigned s0 = 0;
#pragma unroll
    for (int k = 0; k < 2; ++k) { int bq = t * 2 + k; if (bq < nbins) s0 += hist[bq]; }
    partial[t] = s0;
    __syncthreads();
    for (int o = 1; o < STPB; o <<= 1) {
        unsigned v = (t >= o) ? partial[t - o] : 0u;
        __syncthreads();
        partial[t] += v;
        __syncthreads();
    }
    unsigned run = (t == 0) ? 0u : partial[t - 1];
#pragma unroll
    for (int k = 0; k < 2; ++k) {
        int bq = t * 2 + k;
        if (bq < nbins) { bstart[bq] = run; cur[bq] = run; run += hist[bq]; }
    }
    __syncthreads();

    // LDS scatter into bin order
#pragma unroll
    for (int i = 0; i < 8; ++i) {
        if (bn[i] != 0xFFFFu) {
            unsigned p = atomicAdd(&cur[bn[i]], 1u);
            sorted[p] = pay[i];
        }
    }
    __syncthreads();

    // coalesced arena dump + contiguous descriptor dump
    for (int i = t; i < cnt; i += STPB) arena[base + i] = sorted[i];
    for (int bq = t; bq < nbins; bq += STPB) {
        uint2 dd;
        dd.x = (unsigned)(base + bstart[bq]);
        dd.y = hist[bq];
        desc[(long long)blk * nbins + bq] = dd;
    }
}

// ---- build_ell: per-bin segment stitch -> LDS ELL -> coalesced dump -----
// Also writes fc and scales z rows by rsqrt(1+deg) in place.
__global__ __launch_bounds__(256) void build_ell(const uint2* __restrict__ desc,
                                                 const unsigned* __restrict__ arena,
                                                 unsigned* __restrict__ fc,
                                                 unsigned short* __restrict__ ell,
                                                 unsigned* __restrict__ ovf,
                                                 int* __restrict__ ovfList,
                                                 unsigned short* __restrict__ z,
                                                 int n, int nbins, int nblocks) {
    __shared__ unsigned segstart[MAXBLK];
    __shared__ unsigned segpre[MAXBLK];
    __shared__ unsigned pre[256];
    __shared__ unsigned lcnt[MAXDEG];
    __shared__ __align__(16) unsigned short lell[MAXDEG * MAXDEG];  // 8 KB
    const int t   = threadIdx.x;
    const int bin = blockIdx.x;
    const int base = bin * MAXDEG;

    if (t < MAXDEG) lcnt[t] = 0u;

    unsigned len = 0;
    if (t < nblocks) {
        uint2 dd = desc[(long long)t * nbins + bin];  // strided read (cached)
        segstart[t] = dd.x;
        len = dd.y;
    }
    pre[t] = len;
    __syncthreads();
    for (int o = 1; o < 256; o <<= 1) {
        unsigned v = (t >= o) ? pre[t - o] : 0u;
        __syncthreads();
        pre[t] += v;
        __syncthreads();
    }
    const unsigned total = pre[255];
    if (t < nblocks) segpre[t] = pre[t] - len;  // exclusive prefix
    __syncthreads();

    for (unsigned j = t; j < total; j += 256) {
        // largest k with segpre[k] <= j (segpre nondecreasing)
        int lo = 0, hi = nblocks - 1;
        while (lo < hi) {
            int mid = (lo + hi + 1) >> 1;
            if (segpre[mid] <= j) lo = mid; else hi = mid - 1;
        }
        unsigned e  = arena[segstart[lo] + (j - segpre[lo])];
        unsigned dl = e >> 16;
        unsigned c  = atomicAdd(&lcnt[dl], 1u);
        if (c < MAXDEG) {
            lell[dl * MAXDEG + c] = (unsigned short)(e & 0xFFFFu);
        } else {  // deg > 64: exact deg kept in lcnt; extra edge via ovfList
            unsigned p = atomicAdd(ovf, 1u);
            if (p < OVFCAP) {
                ovfList[2 * p]     = (int)(e & 0xFFFFu);
                ovfList[2 * p + 1] = base + (int)dl;
            }
        }
    }
    __syncthreads();

    const int maxrow = (n - base < MAXDEG) ? (n - base) : MAXDEG;
    if (t < maxrow) fc[base + t] = lcnt[t];

    // coalesced ELL dump: maxrow rows x 128B (8 uint4 per row)
    const uint4* lp = (const uint4*)lell;
    uint4* gp = (uint4*)(ell + (long long)base * MAXDEG);
    for (int i = t; i < maxrow * 8; i += 256) gp[i] = lp[i];

    // scale z rows in place: z[row] *= rsqrt(1 + deg)
    uint4* zp = (uint4*)(z + (long long)base * 64);
    for (int i = t; i < maxrow * 8; i += 256) {
        int row = i >> 3;
        float dd = rsqrtf(1.0f + (float)lcnt[row]);
        uint4 v = zp[i];
        v.x = scale2(v.x, dd); v.y = scale2(v.y, dd);
        v.z = scale2(v.z, dd); v.w = scale2(v.w, dd);
        zp[i] = v;
    }
}

// ---- gather: out = relu( dd * (z[node] + sum z[nbr]) + b ) --------------
__global__ __launch_bounds__(256) void gather_z(const unsigned short* __restrict__ ell,
                                                const unsigned* __restrict__ fc,
                                                const unsigned* __restrict__ ovf,
                                                const int* __restrict__ ovfList,
                                                const unsigned short* __restrict__ z,
                                                const float* __restrict__ b,
                                                float* __restrict__ out, int n) {
    const int node = blockIdx.x * 4 + ((int)threadIdx.x >> 6);
    const int lane = threadIdx.x & 63;
    if (node >= n) return;  // wave-uniform

    const unsigned deg = fc[node];
    const float dd = rsqrtf(1.0f + (float)deg);
    float acc = bf2f(z[(unsigned)node * 64 + lane]);  // self-loop term

    const uint4* prow = (const uint4*)(ell + (unsigned)node * MAXDEG);
    const unsigned m = deg < MAXDEG ? deg : MAXDEG;

    unsigned i = 0;
    for (; i + 8 <= m; i += 8) {
        uint4 rw = prow[i >> 3];
        unsigned s[8];
        s[0] = rw.x & 0xFFFFu; s[1] = rw.x >> 16;
        s[2] = rw.y & 0xFFFFu; s[3] = rw.y >> 16;
        s[4] = rw.z & 0xFFFFu; s[5] = rw.z >> 16;
        s[6] = rw.w & 0xFFFFu; s[7] = rw.w >> 16;
        float v[8];
#pragma unroll
        for (int k = 0; k < 8; ++k) v[k] = bf2f(z[s[k] * 64u + lane]);
#pragma unroll
        for (int k = 0; k < 8; ++k) acc += v[k];
    }
    for (; i < m; ++i) {
        unsigned s = ell[(unsigned)node * MAXDEG + i];
        acc += bf2f(z[s * 64u + lane]);
    }

    unsigned nov = *ovf;  // overflow edges: normally zero
    if (nov > 0) {
        nov = nov < OVFCAP ? nov : OVFCAP;
        for (unsigned j = 0; j < nov; ++j)
            if (ovfList[2 * j + 1] == node)
                acc += bf2f(z[(unsigned)ovfList[2 * j] * 64u + lane]);
    }

    out[(unsigned)node * 64 + lane] = fmaxf(fmaf(dd, acc, b[lane]), 0.f);
}

extern "C" void kernel_launch(void* const* d_in, const int* in_sizes, int n_in,
                              void* d_out, int out_size, void* d_ws, size_t ws_size,
                              hipStream_t stream) {
    const float* x  = (const float*)d_in[0];
    const void*  ei = d_in[1];
    const float* W  = (const float*)d_in[2];
    const float* b  = (const float*)d_in[3];
    float* out = (float*)d_out;

    const int n = in_sizes[0] / 64;   // 50000
    const int E = in_sizes[1] / 2;    // 800000
    const int nbins   = (n + MAXDEG - 1) / MAXDEG;  // 782
    const int nblocks = (E + EPB - 1) / EPB;        // 196

    // ws: z[n*64] u16 (6.4M) | ell[n*64] u16 (6.4M) | fc[n] u32 (0.2M) |
    //     ovf u32 | ovfList[2*OVFCAP] | arena[E] u32 (3.2M) |
    //     desc[nblocks*nbins] uint2 (1.23M)  => ~17.5MB (< proven 19.46MB)
    unsigned short* z       = (unsigned short*)d_ws;
    unsigned short* ell     = z + (long long)n * 64;
    unsigned*       fc      = (unsigned*)(ell + (long long)n * 64);
    unsigned*       ovf     = fc + n;
    int*            ovfList = (int*)(ovf + 1);
    unsigned*       arena   = (unsigned*)(ovfList + 2 * OVFCAP);
    uint2*          desc    = (uint2*)(arena + E);

    gemm_z0<<<(n + 31) / 32, TPB, 0, stream>>>(x, W, z, ovf, n);
    binsort<<<nblocks, STPB, 0, stream>>>(ei, arena, desc, E, nbins, nblocks);
    build_ell<<<nbins, TPB, 0, stream>>>(desc, arena, fc, ell, ovf, ovfList, z,
                                         n, nbins, nblocks);
    gather_z<<<(n + 3) / 4, TPB, 0, stream>>>(ell, fc, ovf, ovfList, z, b, out, n);
}

// Round 14
// 83.122 us; speedup vs baseline: 3.2995x; 1.0885x over previous
//
#include <hip/hip_runtime.h>

// GCNBlock: out = relu( D^-1/2 (A+I) D^-1/2 (x@W) + b )
// N=50000, E=800000, D=64, fp32.
// R14: gather restructured to 2 nodes/wave (half-wave per node, lane owns a
// channel PAIR -> 4B loads instead of 2B). Halves gather's load-instruction
// count, doubles payload per outstanding load. R13 LDS-W gemm, binsort,
// build_ell frozen.

#define TPB 256
#define STPB 512      // binsort block size
#define MAXDEG 64
#define OVFCAP 8192
#define EPB 4096      // edges per binsort block
#define MAXBIN 1024   // supports n <= 65536
#define MAXBLK 256    // supports E <= 1M

// ---- per-wave edge dtype detection --------------------------------------
// int64 little-endian with values <2^31 => every odd 32-bit word is 0.
__device__ __forceinline__ int edges_are_i32(const unsigned* __restrict__ w) {
    int lane = threadIdx.x & 63;
    unsigned v = w[1 + 2 * lane];
    return __ballot(v != 0u) != 0ull;
}

__device__ __forceinline__ unsigned short f2bf(float f) {  // RNE to bf16
    unsigned u = __float_as_uint(f);
    u += 0x7FFFu + ((u >> 16) & 1u);
    return (unsigned short)(u >> 16);
}
__device__ __forceinline__ float bf2f(unsigned short h) {
    return __uint_as_float(((unsigned)h) << 16);
}
__device__ __forceinline__ unsigned scale2(unsigned v, float dd) {  // 2 bf16
    unsigned lo = (unsigned)f2bf(dd * bf2f((unsigned short)(v & 0xFFFFu)));
    unsigned hi = (unsigned)f2bf(dd * bf2f((unsigned short)(v >> 16)));
    return lo | (hi << 16);
}

__device__ __forceinline__ void load4(const void* ei, int is32, long long base, int* v) {
    if (is32) {
        int4 a = *(const int4*)((const int*)ei + base);
        v[0] = a.x; v[1] = a.y; v[2] = a.z; v[3] = a.w;
    } else {
        longlong4 a = *(const longlong4*)((const long long*)ei + base);
        v[0] = (int)a.x; v[1] = (int)a.y; v[2] = (int)a.z; v[3] = (int)a.w;
    }
}

// ---- gemm: z0 = bf16(x @ W) via LDS-staged W; zeroes the ovf counter ----
__global__ __launch_bounds__(256) void gemm_z0(const float* __restrict__ x,
                                               const float* __restrict__ W,
                                               unsigned short* __restrict__ z0,
                                               unsigned* __restrict__ ovf, int n) {
    if (blockIdx.x == 0 && threadIdx.x == 0) *ovf = 0u;

    __shared__ float lw[4096];  // W[k*64+c], natural layout, 16 KB
    const int t = threadIdx.x;
#pragma unroll
    for (int i = 0; i < 16; ++i) lw[i * 256 + t] = W[i * 256 + t];
    __syncthreads();

    const int lane = t & 63;
    const int wv   = t >> 6;
    const int row0 = blockIdx.x * 32 + wv * 8;
    if (row0 >= n) return;  // wave-uniform
    const int nr = (n - row0 >= 8) ? 8 : (n - row0);

    float acc[8] = {0.f, 0.f, 0.f, 0.f, 0.f, 0.f, 0.f, 0.f};
#pragma unroll
    for (int k0 = 0; k0 < 16; ++k0) {
        const float w0 = lw[(4 * k0 + 0) * 64 + lane];
        const float w1 = lw[(4 * k0 + 1) * 64 + lane];
        const float w2 = lw[(4 * k0 + 2) * 64 + lane];
        const float w3 = lw[(4 * k0 + 3) * 64 + lane];
#pragma unroll
        for (int r = 0; r < 8; ++r) {
            if (r < nr) {
                float4 xv = *(const float4*)(x + (long long)(row0 + r) * 64 + 4 * k0);
                acc[r] = fmaf(xv.w, w3, fmaf(xv.z, w2, fmaf(xv.y, w1,
                         fmaf(xv.x, w0, acc[r]))));
            }
        }
    }
#pragma unroll
    for (int r = 0; r < 8; ++r)
        if (r < nr) z0[(long long)(row0 + r) * 64 + lane] = f2bf(acc[r]);
}

// ---- binsort: block-local LDS counting sort of 4096 edges by dst>>6 -----
__global__ __launch_bounds__(512) void binsort(const void* __restrict__ ei,
                                               unsigned* __restrict__ arena,
                                               uint2* __restrict__ desc,
                                               int E, int nbins, int nblocks) {
    __shared__ unsigned hist[MAXBIN];
    __shared__ unsigned bstart[MAXBIN];
    __shared__ unsigned cur[MAXBIN];
    __shared__ unsigned sorted[EPB];
    __shared__ unsigned partial[STPB];
    const int t   = threadIdx.x;
    const int blk = blockIdx.x;
    const long long base = (long long)blk * EPB;
    const int cnt = (int)((E - base < EPB) ? (E - base) : EPB);
    const int is32 = edges_are_i32((const unsigned*)ei);

    for (int i = t; i < nbins; i += STPB) hist[i] = 0u;
    __syncthreads();

    unsigned pay[8];
    unsigned short bn[8];
#pragma unroll
    for (int r = 0; r < 2; ++r) {
        const int lo = r * (STPB * 4) + t * 4;  // local offset of this 4-pack
        if (lo + 4 <= cnt) {
            int s4[4], d4[4];
            load4(ei, is32, base + lo, s4);
            load4(ei, is32, (long long)E + base + lo, d4);
#pragma unroll
            for (int k = 0; k < 4; ++k) {
                pay[r * 4 + k] = ((unsigned)(d4[k] & 63) << 16) | (unsigned)s4[k];
                bn[r * 4 + k]  = (unsigned short)((unsigned)d4[k] >> 6);
                atomicAdd(&hist[bn[r * 4 + k]], 1u);
            }
        } else {
#pragma unroll
            for (int k = 0; k < 4; ++k) {
                int l = lo + k;
                if (l < cnt) {
                    int s_, d_;
                    if (is32) {
                        s_ = ((const int*)ei)[base + l];
                        d_ = ((const int*)ei)[(long long)E + base + l];
                    } else {
                        s_ = (int)((const long long*)ei)[base + l];
                        d_ = (int)((const long long*)ei)[(long long)E + base + l];
                    }
                    pay[r * 4 + k] = ((unsigned)(d_ & 63) << 16) | (unsigned)s_;
                    bn[r * 4 + k]  = (unsigned short)((unsigned)d_ >> 6);
                    atomicAdd(&hist[bn[r * 4 + k]], 1u);
                } else {
                    bn[r * 4 + k] = 0xFFFFu;  // invalid sentinel
                }
            }
        }
    }
    __syncthreads();

    // exclusive prefix over nbins (2 bins per thread + 512-wide scan)
    unsigned s0 = 0;
#pragma unroll
    for (int k = 0; k < 2; ++k) { int bq = t * 2 + k; if (bq < nbins) s0 += hist[bq]; }
    partial[t] = s0;
    __syncthreads();
    for (int o = 1; o < STPB; o <<= 1) {
        unsigned v = (t >= o) ? partial[t - o] : 0u;
        __syncthreads();
        partial[t] += v;
        __syncthreads();
    }
    unsigned run = (t == 0) ? 0u : partial[t - 1];
#pragma unroll
    for (int k = 0; k < 2; ++k) {
        int bq = t * 2 + k;
        if (bq < nbins) { bstart[bq] = run; cur[bq] = run; run += hist[bq]; }
    }
    __syncthreads();

    // LDS scatter into bin order
#pragma unroll
    for (int i = 0; i < 8; ++i) {
        if (bn[i] != 0xFFFFu) {
            unsigned p = atomicAdd(&cur[bn[i]], 1u);
            sorted[p] = pay[i];
        }
    }
    __syncthreads();

    // coalesced arena dump + contiguous descriptor dump
    for (int i = t; i < cnt; i += STPB) arena[base + i] = sorted[i];
    for (int bq = t; bq < nbins; bq += STPB) {
        uint2 dd;
        dd.x = (unsigned)(base + bstart[bq]);
        dd.y = hist[bq];
        desc[(long long)blk * nbins + bq] = dd;
    }
}

// ---- build_ell: per-bin segment stitch -> LDS ELL -> coalesced dump -----
__global__ __launch_bounds__(256) void build_ell(const uint2* __restrict__ desc,
                                                 const unsigned* __restrict__ arena,
                                                 unsigned* __restrict__ fc,
                                                 unsigned short* __restrict__ ell,
                                                 unsigned* __restrict__ ovf,
                                                 int* __restrict__ ovfList,
                                                 unsigned short* __restrict__ z,
                                                 int n, int nbins, int nblocks) {
    __shared__ unsigned segstart[MAXBLK];
    __shared__ unsigned segpre[MAXBLK];
    __shared__ unsigned pre[256];
    __shared__ unsigned lcnt[MAXDEG];
    __shared__ __align__(16) unsigned short lell[MAXDEG * MAXDEG];  // 8 KB
    const int t   = threadIdx.x;
    const int bin = blockIdx.x;
    const int base = bin * MAXDEG;

    if (t < MAXDEG) lcnt[t] = 0u;

    unsigned len = 0;
    if (t < nblocks) {
        uint2 dd = desc[(long long)t * nbins + bin];  // strided read (cached)
        segstart[t] = dd.x;
        len = dd.y;
    }
    pre[t] = len;
    __syncthreads();
    for (int o = 1; o < 256; o <<= 1) {
        unsigned v = (t >= o) ? pre[t - o] : 0u;
        __syncthreads();
        pre[t] += v;
        __syncthreads();
    }
    const unsigned total = pre[255];
    if (t < nblocks) segpre[t] = pre[t] - len;  // exclusive prefix
    __syncthreads();

    for (unsigned j = t; j < total; j += 256) {
        // largest k with segpre[k] <= j (segpre nondecreasing)
        int lo = 0, hi = nblocks - 1;
        while (lo < hi) {
            int mid = (lo + hi + 1) >> 1;
            if (segpre[mid] <= j) lo = mid; else hi = mid - 1;
        }
        unsigned e  = arena[segstart[lo] + (j - segpre[lo])];
        unsigned dl = e >> 16;
        unsigned c  = atomicAdd(&lcnt[dl], 1u);
        if (c < MAXDEG) {
            lell[dl * MAXDEG + c] = (unsigned short)(e & 0xFFFFu);
        } else {  // deg > 64: exact deg kept in lcnt; extra edge via ovfList
            unsigned p = atomicAdd(ovf, 1u);
            if (p < OVFCAP) {
                ovfList[2 * p]     = (int)(e & 0xFFFFu);
                ovfList[2 * p + 1] = base + (int)dl;
            }
        }
    }
    __syncthreads();

    const int maxrow = (n - base < MAXDEG) ? (n - base) : MAXDEG;
    if (t < maxrow) fc[base + t] = lcnt[t];

    // coalesced ELL dump: maxrow rows x 128B (8 uint4 per row)
    const uint4* lp = (const uint4*)lell;
    uint4* gp = (uint4*)(ell + (long long)base * MAXDEG);
    for (int i = t; i < maxrow * 8; i += 256) gp[i] = lp[i];

    // scale z rows in place: z[row] *= rsqrt(1 + deg)
    uint4* zp = (uint4*)(z + (long long)base * 64);
    for (int i = t; i < maxrow * 8; i += 256) {
        int row = i >> 3;
        float dd = rsqrtf(1.0f + (float)lcnt[row]);
        uint4 v = zp[i];
        v.x = scale2(v.x, dd); v.y = scale2(v.y, dd);
        v.z = scale2(v.z, dd); v.w = scale2(v.w, dd);
        zp[i] = v;
    }
}

// ---- gather: 2 nodes per wave; lane owns a channel pair (4B loads) ------
// out = relu( dd * (z[node] + sum z[nbr]) + b )
__global__ __launch_bounds__(256) void gather_z(const unsigned short* __restrict__ ell,
                                                const unsigned* __restrict__ fc,
                                                const unsigned* __restrict__ ovf,
                                                const int* __restrict__ ovfList,
                                                const unsigned short* __restrict__ z,
                                                const float* __restrict__ b,
                                                float* __restrict__ out, int n) {
    const int wv   = (int)threadIdx.x >> 6;
    const int lane = threadIdx.x & 63;
    const int half = lane >> 5;       // which node of the pair
    const int cp   = lane & 31;       // channel pair (2 bf16 = 1 uint)
    const int node = (blockIdx.x * 4 + wv) * 2 + half;
    const bool valid = node < n;
    const int nodec = valid ? node : (n - 1);  // clamped for safe addressing

    const unsigned deg = valid ? fc[nodec] : 0u;
    const float dd = rsqrtf(1.0f + (float)deg);

    unsigned zs = *(const unsigned*)(z + (unsigned)nodec * 64 + cp * 2);
    float acc0 = bf2f((unsigned short)(zs & 0xFFFFu));   // self-loop term
    float acc1 = bf2f((unsigned short)(zs >> 16));

    unsigned m = deg < MAXDEG ? deg : MAXDEG;
    if (!valid) m = 0u;
    const unsigned mo = __shfl_xor((int)m, 32);          // other half's m
    const unsigned mmax = m > mo ? m : mo;               // wave-uniform trips

    const uint4* prow = (const uint4*)(ell + (unsigned)nodec * MAXDEG);

    unsigned i = 0;
    for (; i + 8 <= mmax; i += 8) {
        uint4 rw = prow[i >> 3];      // per-half broadcast of 8 ids
        unsigned s[8];
        s[0] = rw.x & 0xFFFFu; s[1] = rw.x >> 16;
        s[2] = rw.y & 0xFFFFu; s[3] = rw.y >> 16;
        s[4] = rw.z & 0xFFFFu; s[5] = rw.z >> 16;
        s[6] = rw.w & 0xFFFFu; s[7] = rw.w >> 16;
        if (i + 8 <= m) {             // full batch for this half
            unsigned v[8];
#pragma unroll
            for (int k = 0; k < 8; ++k)
                v[k] = *(const unsigned*)(z + s[k] * 64u + cp * 2);
#pragma unroll
            for (int k = 0; k < 8; ++k) {
                acc0 += bf2f((unsigned short)(v[k] & 0xFFFFu));
                acc1 += bf2f((unsigned short)(v[k] >> 16));
            }
        } else {                      // partial batch (divergent tail)
#pragma unroll
            for (int k = 0; k < 8; ++k) {
                if (i + k < m) {
                    unsigned v = *(const unsigned*)(z + s[k] * 64u + cp * 2);
                    acc0 += bf2f((unsigned short)(v & 0xFFFFu));
                    acc1 += bf2f((unsigned short)(v >> 16));
                }
            }
        }
    }
    for (; i < mmax; ++i) {
        if (i < m) {
            unsigned s = ell[(unsigned)nodec * MAXDEG + i];
            unsigned v = *(const unsigned*)(z + s * 64u + cp * 2);
            acc0 += bf2f((unsigned short)(v & 0xFFFFu));
            acc1 += bf2f((unsigned short)(v >> 16));
        }
    }

    unsigned nov = *ovf;  // overflow edges: normally zero
    if (nov > 0) {
        nov = nov < OVFCAP ? nov : OVFCAP;
        for (unsigned j = 0; j < nov; ++j)
            if (valid && ovfList[2 * j + 1] == node) {
                unsigned v = *(const unsigned*)(z + (unsigned)ovfList[2 * j] * 64u + cp * 2);
                acc0 += bf2f((unsigned short)(v & 0xFFFFu));
                acc1 += bf2f((unsigned short)(v >> 16));
            }
    }

    if (valid) {
        float2 o;
        o.x = fmaxf(fmaf(dd, acc0, b[cp * 2 + 0]), 0.f);
        o.y = fmaxf(fmaf(dd, acc1, b[cp * 2 + 1]), 0.f);
        *(float2*)(out + (unsigned)node * 64 + cp * 2) = o;
    }
}

extern "C" void kernel_launch(void* const* d_in, const int* in_sizes, int n_in,
                              void* d_out, int out_size, void* d_ws, size_t ws_size,
                              hipStream_t stream) {
    const float* x  = (const float*)d_in[0];
    const void*  ei = d_in[1];
    const float* W  = (const float*)d_in[2];
    const float* b  = (const float*)d_in[3];
    float* out = (float*)d_out;

    const int n = in_sizes[0] / 64;   // 50000
    const int E = in_sizes[1] / 2;    // 800000
    const int nbins   = (n + MAXDEG - 1) / MAXDEG;  // 782
    const int nblocks = (E + EPB - 1) / EPB;        // 196

    // ws: z[n*64] u16 (6.4M) | ell[n*64] u16 (6.4M) | fc[n] u32 (0.2M) |
    //     ovf u32 | ovfList[2*OVFCAP] | arena[E] u32 (3.2M) |
    //     desc[nblocks*nbins] uint2 (1.23M)  => ~17.5MB (< proven 19.46MB)
    unsigned short* z       = (unsigned short*)d_ws;
    unsigned short* ell     = z + (long long)n * 64;
    unsigned*       fc      = (unsigned*)(ell + (long long)n * 64);
    unsigned*       ovf     = fc + n;
    int*            ovfList = (int*)(ovf + 1);
    unsigned*       arena   = (unsigned*)(ovfList + 2 * OVFCAP);
    uint2*          desc    = (uint2*)(arena + E);

    gemm_z0<<<(n + 31) / 32, TPB, 0, stream>>>(x, W, z, ovf, n);
    binsort<<<nblocks, STPB, 0, stream>>>(ei, arena, desc, E, nbins, nblocks);
    build_ell<<<nbins, TPB, 0, stream>>>(desc, arena, fc, ell, ovf, ovfList, z,
                                         n, nbins, nblocks);
    gather_z<<<(n + 7) / 8, TPB, 0, stream>>>(ell, fc, ovf, ovfList, z, b, out, n);
}

// Round 15
// 80.918 us; speedup vs baseline: 3.3894x; 1.0272x over previous
//
#include <hip/hip_runtime.h>

// GCNBlock: out = relu( D^-1/2 (A+I) D^-1/2 (x@W) + b )
// N=50000, E=800000, D=64, fp32.
// R15: binsort EPB 4096->2048 (196->391 blocks, was 0.77 blocks/CU) and gemm
// FUSED into the binsort launch via block split (independent phases; LDS-W
// gemm has no big register array so the R4/R7 spill trap doesn't apply).
// build_ell upgraded to 512-segment scan (nblocks=391 > 256). gather frozen.

#define TPB 256
#define STPB 512      // fused kernel block size
#define MAXDEG 64
#define OVFCAP 8192
#define EPB 2048      // edges per binsort block
#define MAXBIN 1024   // supports n <= 65536
#define MAXBLK 512    // supports E <= 1M (512*2048)

// ---- per-wave edge dtype detection --------------------------------------
// int64 little-endian with values <2^31 => every odd 32-bit word is 0.
__device__ __forceinline__ int edges_are_i32(const unsigned* __restrict__ w) {
    int lane = threadIdx.x & 63;
    unsigned v = w[1 + 2 * lane];
    return __ballot(v != 0u) != 0ull;
}

__device__ __forceinline__ unsigned short f2bf(float f) {  // RNE to bf16
    unsigned u = __float_as_uint(f);
    u += 0x7FFFu + ((u >> 16) & 1u);
    return (unsigned short)(u >> 16);
}
__device__ __forceinline__ float bf2f(unsigned short h) {
    return __uint_as_float(((unsigned)h) << 16);
}
__device__ __forceinline__ unsigned scale2(unsigned v, float dd) {  // 2 bf16
    unsigned lo = (unsigned)f2bf(dd * bf2f((unsigned short)(v & 0xFFFFu)));
    unsigned hi = (unsigned)f2bf(dd * bf2f((unsigned short)(v >> 16)));
    return lo | (hi << 16);
}

__device__ __forceinline__ void load4(const void* ei, int is32, long long base, int* v) {
    if (is32) {
        int4 a = *(const int4*)((const int*)ei + base);
        v[0] = a.x; v[1] = a.y; v[2] = a.z; v[3] = a.w;
    } else {
        longlong4 a = *(const longlong4*)((const long long*)ei + base);
        v[0] = (int)a.x; v[1] = (int)a.y; v[2] = (int)a.z; v[3] = (int)a.w;
    }
}

// ---- fused: gemm z0=bf16(x@W) (blocks < gemmBlocks) || binsort (rest) ---
// LDS union: gemm uses 16KB (W stage), binsort 22KB (hist/cursors/sorted).
__global__ __launch_bounds__(512) void gemm_binsort(
        const float* __restrict__ x, const float* __restrict__ W,
        unsigned short* __restrict__ z0, unsigned* __restrict__ ovf,
        const void* __restrict__ ei, unsigned* __restrict__ arena,
        uint2* __restrict__ desc, int E, int nbins, int nblocks,
        int n, int gemmBlocks) {
    __shared__ __align__(16) unsigned char smem[22528];  // max(16KB, 22KB)
    const int t = threadIdx.x;

    if ((int)blockIdx.x < gemmBlocks) {
        // ---- gemm: LDS-staged W; lane = column; 8 waves x 8 rows ----
        if (blockIdx.x == 0 && t == 0) *ovf = 0u;
        float* lw = (float*)smem;  // W[k*64+c], 16 KB
#pragma unroll
        for (int i = 0; i < 8; ++i) lw[i * 512 + t] = W[i * 512 + t];
        __syncthreads();

        const int lane = t & 63;
        const int wv   = t >> 6;                  // 0..7
        const int row0 = blockIdx.x * 64 + wv * 8;
        if (row0 >= n) return;  // wave-uniform
        const int nr = (n - row0 >= 8) ? 8 : (n - row0);

        float acc[8] = {0.f, 0.f, 0.f, 0.f, 0.f, 0.f, 0.f, 0.f};
#pragma unroll
        for (int k0 = 0; k0 < 16; ++k0) {
            const float w0 = lw[(4 * k0 + 0) * 64 + lane];
            const float w1 = lw[(4 * k0 + 1) * 64 + lane];
            const float w2 = lw[(4 * k0 + 2) * 64 + lane];
            const float w3 = lw[(4 * k0 + 3) * 64 + lane];
#pragma unroll
            for (int r = 0; r < 8; ++r) {
                if (r < nr) {
                    float4 xv = *(const float4*)(x + (long long)(row0 + r) * 64 + 4 * k0);
                    acc[r] = fmaf(xv.w, w3, fmaf(xv.z, w2, fmaf(xv.y, w1,
                             fmaf(xv.x, w0, acc[r]))));
                }
            }
        }
#pragma unroll
        for (int r = 0; r < 8; ++r)
            if (r < nr) z0[(long long)(row0 + r) * 64 + lane] = f2bf(acc[r]);
        return;
    }

    // ---- binsort: LDS counting sort of 2048 edges by dst>>6 ----
    unsigned* hist    = (unsigned*)smem;            // [MAXBIN]
    unsigned* bstart  = hist + MAXBIN;              // [MAXBIN]
    unsigned* cur     = bstart + MAXBIN;            // [MAXBIN]
    unsigned* sorted  = cur + MAXBIN;               // [EPB]
    unsigned* partial = sorted + EPB;               // [STPB]
    const int blk = (int)blockIdx.x - gemmBlocks;
    const long long base = (long long)blk * EPB;
    const int cnt = (int)((E - base < EPB) ? (E - base) : EPB);
    const int is32 = edges_are_i32((const unsigned*)ei);

    for (int i = t; i < nbins; i += STPB) hist[i] = 0u;
    __syncthreads();

    unsigned pay[4];
    unsigned short bn[4];
    {
        const int lo = t * 4;
        if (lo + 4 <= cnt) {
            int s4[4], d4[4];
            load4(ei, is32, base + lo, s4);
            load4(ei, is32, (long long)E + base + lo, d4);
#pragma unroll
            for (int k = 0; k < 4; ++k) {
                pay[k] = ((unsigned)(d4[k] & 63) << 16) | (unsigned)s4[k];
                bn[k]  = (unsigned short)((unsigned)d4[k] >> 6);
                atomicAdd(&hist[bn[k]], 1u);
            }
        } else {
#pragma unroll
            for (int k = 0; k < 4; ++k) {
                int l = lo + k;
                if (l < cnt) {
                    int s_, d_;
                    if (is32) {
                        s_ = ((const int*)ei)[base + l];
                        d_ = ((const int*)ei)[(long long)E + base + l];
                    } else {
                        s_ = (int)((const long long*)ei)[base + l];
                        d_ = (int)((const long long*)ei)[(long long)E + base + l];
                    }
                    pay[k] = ((unsigned)(d_ & 63) << 16) | (unsigned)s_;
                    bn[k]  = (unsigned short)((unsigned)d_ >> 6);
                    atomicAdd(&hist[bn[k]], 1u);
                } else {
                    bn[k] = 0xFFFFu;  // invalid sentinel
                }
            }
        }
    }
    __syncthreads();

    // exclusive prefix over nbins (2 bins per thread + 512-wide scan)
    unsigned s0 = 0;
#pragma unroll
    for (int k = 0; k < 2; ++k) { int bq = t * 2 + k; if (bq < nbins) s0 += hist[bq]; }
    partial[t] = s0;
    __syncthreads();
    for (int o = 1; o < STPB; o <<= 1) {
        unsigned v = (t >= o) ? partial[t - o] : 0u;
        __syncthreads();
        partial[t] += v;
        __syncthreads();
    }
    unsigned run = (t == 0) ? 0u : partial[t - 1];
#pragma unroll
    for (int k = 0; k < 2; ++k) {
        int bq = t * 2 + k;
        if (bq < nbins) { bstart[bq] = run; cur[bq] = run; run += hist[bq]; }
    }
    __syncthreads();

    // LDS scatter into bin order
#pragma unroll
    for (int i = 0; i < 4; ++i) {
        if (bn[i] != 0xFFFFu) {
            unsigned p = atomicAdd(&cur[bn[i]], 1u);
            sorted[p] = pay[i];
        }
    }
    __syncthreads();

    // coalesced arena dump + contiguous descriptor dump
    for (int i = t; i < cnt; i += STPB) arena[base + i] = sorted[i];
    for (int bq = t; bq < nbins; bq += STPB) {
        uint2 dd;
        dd.x = (unsigned)(base + bstart[bq]);
        dd.y = hist[bq];
        desc[(long long)blk * nbins + bq] = dd;
    }
}

// ---- build_ell: per-bin segment stitch (up to 512 segs) -> LDS ELL ------
// Also writes fc and scales z rows by rsqrt(1+deg) in place.
__global__ __launch_bounds__(256) void build_ell(const uint2* __restrict__ desc,
                                                 const unsigned* __restrict__ arena,
                                                 unsigned* __restrict__ fc,
                                                 unsigned short* __restrict__ ell,
                                                 unsigned* __restrict__ ovf,
                                                 int* __restrict__ ovfList,
                                                 unsigned short* __restrict__ z,
                                                 int n, int nbins, int nblocks) {
    __shared__ unsigned segstart[MAXBLK];
    __shared__ unsigned segpre[MAXBLK];
    __shared__ unsigned pre[MAXBLK];
    __shared__ unsigned lcnt[MAXDEG];
    __shared__ __align__(16) unsigned short lell[MAXDEG * MAXDEG];  // 8 KB
    const int t   = threadIdx.x;
    const int bin = blockIdx.x;
    const int base = bin * MAXDEG;

    if (t < MAXDEG) lcnt[t] = 0u;

    unsigned len0 = 0, len1 = 0;
    if (t < nblocks) {
        uint2 dd = desc[(long long)t * nbins + bin];
        segstart[t] = dd.x;
        len0 = dd.y;
    }
    if (t + 256 < nblocks) {
        uint2 dd = desc[(long long)(t + 256) * nbins + bin];
        segstart[t + 256] = dd.x;
        len1 = dd.y;
    }
    pre[t] = len0;
    pre[t + 256] = len1;
    __syncthreads();
    // scan both 256-halves simultaneously, then offset the upper half
    for (int o = 1; o < 256; o <<= 1) {
        unsigned vA = (t >= o) ? pre[t - o] : 0u;
        unsigned vB = (t >= o) ? pre[256 + t - o] : 0u;
        __syncthreads();
        pre[t] += vA;
        pre[256 + t] += vB;
        __syncthreads();
    }
    const unsigned lowTot = pre[255];
    pre[256 + t] += lowTot;   // no thread writes pre[255] here
    __syncthreads();
    const unsigned total = pre[MAXBLK - 1];
    if (t < nblocks) segpre[t] = pre[t] - len0;
    if (t + 256 < nblocks) segpre[t + 256] = pre[256 + t] - len1;
    __syncthreads();

    for (unsigned j = t; j < total; j += 256) {
        // largest k with segpre[k] <= j (segpre nondecreasing)
        int lo = 0, hi = nblocks - 1;
        while (lo < hi) {
            int mid = (lo + hi + 1) >> 1;
            if (segpre[mid] <= j) lo = mid; else hi = mid - 1;
        }
        unsigned e  = arena[segstart[lo] + (j - segpre[lo])];
        unsigned dl = e >> 16;
        unsigned c  = atomicAdd(&lcnt[dl], 1u);
        if (c < MAXDEG) {
            lell[dl * MAXDEG + c] = (unsigned short)(e & 0xFFFFu);
        } else {  // deg > 64: exact deg kept in lcnt; extra edge via ovfList
            unsigned p = atomicAdd(ovf, 1u);
            if (p < OVFCAP) {
                ovfList[2 * p]     = (int)(e & 0xFFFFu);
                ovfList[2 * p + 1] = base + (int)dl;
            }
        }
    }
    __syncthreads();

    const int maxrow = (n - base < MAXDEG) ? (n - base) : MAXDEG;
    if (t < maxrow) fc[base + t] = lcnt[t];

    // coalesced ELL dump: maxrow rows x 128B (8 uint4 per row)
    const uint4* lp = (const uint4*)lell;
    uint4* gp = (uint4*)(ell + (long long)base * MAXDEG);
    for (int i = t; i < maxrow * 8; i += 256) gp[i] = lp[i];

    // scale z rows in place: z[row] *= rsqrt(1 + deg)
    uint4* zp = (uint4*)(z + (long long)base * 64);
    for (int i = t; i < maxrow * 8; i += 256) {
        int row = i >> 3;
        float dd = rsqrtf(1.0f + (float)lcnt[row]);
        uint4 v = zp[i];
        v.x = scale2(v.x, dd); v.y = scale2(v.y, dd);
        v.z = scale2(v.z, dd); v.w = scale2(v.w, dd);
        zp[i] = v;
    }
}

// ---- gather: 2 nodes per wave; lane owns a channel pair (4B loads) ------
__global__ __launch_bounds__(256) void gather_z(const unsigned short* __restrict__ ell,
                                                const unsigned* __restrict__ fc,
                                                const unsigned* __restrict__ ovf,
                                                const int* __restrict__ ovfList,
                                                const unsigned short* __restrict__ z,
                                                const float* __restrict__ b,
                                                float* __restrict__ out, int n) {
    const int wv   = (int)threadIdx.x >> 6;
    const int lane = threadIdx.x & 63;
    const int half = lane >> 5;       // which node of the pair
    const int cp   = lane & 31;       // channel pair (2 bf16 = 1 uint)
    const int node = (blockIdx.x * 4 + wv) * 2 + half;
    const bool valid = node < n;
    const int nodec = valid ? node : (n - 1);  // clamped for safe addressing

    const unsigned deg = valid ? fc[nodec] : 0u;
    const float dd = rsqrtf(1.0f + (float)deg);

    unsigned zs = *(const unsigned*)(z + (unsigned)nodec * 64 + cp * 2);
    float acc0 = bf2f((unsigned short)(zs & 0xFFFFu));   // self-loop term
    float acc1 = bf2f((unsigned short)(zs >> 16));

    unsigned m = deg < MAXDEG ? deg : MAXDEG;
    if (!valid) m = 0u;
    const unsigned mo = __shfl_xor((int)m, 32);          // other half's m
    const unsigned mmax = m > mo ? m : mo;               // wave-uniform trips

    const uint4* prow = (const uint4*)(ell + (unsigned)nodec * MAXDEG);

    unsigned i = 0;
    for (; i + 8 <= mmax; i += 8) {
        uint4 rw = prow[i >> 3];      // per-half broadcast of 8 ids
        unsigned s[8];
        s[0] = rw.x & 0xFFFFu; s[1] = rw.x >> 16;
        s[2] = rw.y & 0xFFFFu; s[3] = rw.y >> 16;
        s[4] = rw.z & 0xFFFFu; s[5] = rw.z >> 16;
        s[6] = rw.w & 0xFFFFu; s[7] = rw.w >> 16;
        if (i + 8 <= m) {             // full batch for this half
            unsigned v[8];
#pragma unroll
            for (int k = 0; k < 8; ++k)
                v[k] = *(const unsigned*)(z + s[k] * 64u + cp * 2);
#pragma unroll
            for (int k = 0; k < 8; ++k) {
                acc0 += bf2f((unsigned short)(v[k] & 0xFFFFu));
                acc1 += bf2f((unsigned short)(v[k] >> 16));
            }
        } else {                      // partial batch (divergent tail)
#pragma unroll
            for (int k = 0; k < 8; ++k) {
                if (i + k < m) {
                    unsigned v = *(const unsigned*)(z + s[k] * 64u + cp * 2);
                    acc0 += bf2f((unsigned short)(v & 0xFFFFu));
                    acc1 += bf2f((unsigned short)(v >> 16));
                }
            }
        }
    }
    for (; i < mmax; ++i) {
        if (i < m) {
            unsigned s = ell[(unsigned)nodec * MAXDEG + i];
            unsigned v = *(const unsigned*)(z + s * 64u + cp * 2);
            acc0 += bf2f((unsigned short)(v & 0xFFFFu));
            acc1 += bf2f((unsigned short)(v >> 16));
        }
    }

    unsigned nov = *ovf;  // overflow edges: normally zero
    if (nov > 0) {
        nov = nov < OVFCAP ? nov : OVFCAP;
        for (unsigned j = 0; j < nov; ++j)
            if (valid && ovfList[2 * j + 1] == node) {
                unsigned v = *(const unsigned*)(z + (unsigned)ovfList[2 * j] * 64u + cp * 2);
                acc0 += bf2f((unsigned short)(v & 0xFFFFu));
                acc1 += bf2f((unsigned short)(v >> 16));
            }
    }

    if (valid) {
        float2 o;
        o.x = fmaxf(fmaf(dd, acc0, b[cp * 2 + 0]), 0.f);
        o.y = fmaxf(fmaf(dd, acc1, b[cp * 2 + 1]), 0.f);
        *(float2*)(out + (unsigned)node * 64 + cp * 2) = o;
    }
}

extern "C" void kernel_launch(void* const* d_in, const int* in_sizes, int n_in,
                              void* d_out, int out_size, void* d_ws, size_t ws_size,
                              hipStream_t stream) {
    const float* x  = (const float*)d_in[0];
    const void*  ei = d_in[1];
    const float* W  = (const float*)d_in[2];
    const float* b  = (const float*)d_in[3];
    float* out = (float*)d_out;

    const int n = in_sizes[0] / 64;   // 50000
    const int E = in_sizes[1] / 2;    // 800000
    const int nbins   = (n + MAXDEG - 1) / MAXDEG;  // 782
    const int nblocks = (E + EPB - 1) / EPB;        // 391
    const int gemmBlocks = (n + 63) / 64;           // 782

    // ws: z[n*64] u16 (6.4M) | ell[n*64] u16 (6.4M) | fc[n] u32 (0.2M) |
    //     ovf u32 | ovfList[2*OVFCAP] (64K) | arena[E] u32 (3.2M) |
    //     desc[nblocks*nbins] uint2 (2.45M)  => ~18.7MB (< proven 19.46MB)
    unsigned short* z       = (unsigned short*)d_ws;
    unsigned short* ell     = z + (long long)n * 64;
    unsigned*       fc      = (unsigned*)(ell + (long long)n * 64);
    unsigned*       ovf     = fc + n;
    int*            ovfList = (int*)(ovf + 1);
    unsigned*       arena   = (unsigned*)(ovfList + 2 * OVFCAP);
    uint2*          desc    = (uint2*)(arena + E);

    gemm_binsort<<<gemmBlocks + nblocks, STPB, 0, stream>>>(
        x, W, z, ovf, ei, arena, desc, E, nbins, nblocks, n, gemmBlocks);
    build_ell<<<nbins, TPB, 0, stream>>>(desc, arena, fc, ell, ovf, ovfList, z,
                                         n, nbins, nblocks);
    gather_z<<<(n + 7) / 8, TPB, 0, stream>>>(ell, fc, ovf, ovfList, z, b, out, n);
}

// Round 16
// 78.457 us; speedup vs baseline: 3.4957x; 1.0314x over previous
//
#include <hip/hip_runtime.h>

// GCNBlock: out = relu( D^-1/2 (A+I) D^-1/2 (x@W) + b )
// N=50000, E=800000, D=64, fp32.
// R16: gather to 4 nodes/wave (quarter-wave per node, lane owns 4 channels
// via uint2 8B loads). Halves gather's load-instruction count again (R14's
// 2-nodes/wave bought 7us -> gather is issue/latency-bound). Rest frozen.

#define TPB 256
#define STPB 512      // fused kernel block size
#define MAXDEG 64
#define OVFCAP 8192
#define EPB 2048      // edges per binsort block
#define MAXBIN 1024   // supports n <= 65536
#define MAXBLK 512    // supports E <= 1M (512*2048)

// ---- per-wave edge dtype detection --------------------------------------
// int64 little-endian with values <2^31 => every odd 32-bit word is 0.
__device__ __forceinline__ int edges_are_i32(const unsigned* __restrict__ w) {
    int lane = threadIdx.x & 63;
    unsigned v = w[1 + 2 * lane];
    return __ballot(v != 0u) != 0ull;
}

__device__ __forceinline__ unsigned short f2bf(float f) {  // RNE to bf16
    unsigned u = __float_as_uint(f);
    u += 0x7FFFu + ((u >> 16) & 1u);
    return (unsigned short)(u >> 16);
}
__device__ __forceinline__ float bf2f(unsigned short h) {
    return __uint_as_float(((unsigned)h) << 16);
}
__device__ __forceinline__ unsigned scale2(unsigned v, float dd) {  // 2 bf16
    unsigned lo = (unsigned)f2bf(dd * bf2f((unsigned short)(v & 0xFFFFu)));
    unsigned hi = (unsigned)f2bf(dd * bf2f((unsigned short)(v >> 16)));
    return lo | (hi << 16);
}

__device__ __forceinline__ void load4(const void* ei, int is32, long long base, int* v) {
    if (is32) {
        int4 a = *(const int4*)((const int*)ei + base);
        v[0] = a.x; v[1] = a.y; v[2] = a.z; v[3] = a.w;
    } else {
        longlong4 a = *(const longlong4*)((const long long*)ei + base);
        v[0] = (int)a.x; v[1] = (int)a.y; v[2] = (int)a.z; v[3] = (int)a.w;
    }
}

// ---- fused: gemm z0=bf16(x@W) (blocks < gemmBlocks) || binsort (rest) ---
__global__ __launch_bounds__(512) void gemm_binsort(
        const float* __restrict__ x, const float* __restrict__ W,
        unsigned short* __restrict__ z0, unsigned* __restrict__ ovf,
        const void* __restrict__ ei, unsigned* __restrict__ arena,
        uint2* __restrict__ desc, int E, int nbins, int nblocks,
        int n, int gemmBlocks) {
    __shared__ __align__(16) unsigned char smem[22528];  // max(16KB, 22KB)
    const int t = threadIdx.x;

    if ((int)blockIdx.x < gemmBlocks) {
        // ---- gemm: LDS-staged W; lane = column; 8 waves x 8 rows ----
        if (blockIdx.x == 0 && t == 0) *ovf = 0u;
        float* lw = (float*)smem;  // W[k*64+c], 16 KB
#pragma unroll
        for (int i = 0; i < 8; ++i) lw[i * 512 + t] = W[i * 512 + t];
        __syncthreads();

        const int lane = t & 63;
        const int wv   = t >> 6;                  // 0..7
        const int row0 = blockIdx.x * 64 + wv * 8;
        if (row0 >= n) return;  // wave-uniform
        const int nr = (n - row0 >= 8) ? 8 : (n - row0);

        float acc[8] = {0.f, 0.f, 0.f, 0.f, 0.f, 0.f, 0.f, 0.f};
#pragma unroll
        for (int k0 = 0; k0 < 16; ++k0) {
            const float w0 = lw[(4 * k0 + 0) * 64 + lane];
            const float w1 = lw[(4 * k0 + 1) * 64 + lane];
            const float w2 = lw[(4 * k0 + 2) * 64 + lane];
            const float w3 = lw[(4 * k0 + 3) * 64 + lane];
#pragma unroll
            for (int r = 0; r < 8; ++r) {
                if (r < nr) {
                    float4 xv = *(const float4*)(x + (long long)(row0 + r) * 64 + 4 * k0);
                    acc[r] = fmaf(xv.w, w3, fmaf(xv.z, w2, fmaf(xv.y, w1,
                             fmaf(xv.x, w0, acc[r]))));
                }
            }
        }
#pragma unroll
        for (int r = 0; r < 8; ++r)
            if (r < nr) z0[(long long)(row0 + r) * 64 + lane] = f2bf(acc[r]);
        return;
    }

    // ---- binsort: LDS counting sort of 2048 edges by dst>>6 ----
    unsigned* hist    = (unsigned*)smem;            // [MAXBIN]
    unsigned* bstart  = hist + MAXBIN;              // [MAXBIN]
    unsigned* cur     = bstart + MAXBIN;            // [MAXBIN]
    unsigned* sorted  = cur + MAXBIN;               // [EPB]
    unsigned* partial = sorted + EPB;               // [STPB]
    const int blk = (int)blockIdx.x - gemmBlocks;
    const long long base = (long long)blk * EPB;
    const int cnt = (int)((E - base < EPB) ? (E - base) : EPB);
    const int is32 = edges_are_i32((const unsigned*)ei);

    for (int i = t; i < nbins; i += STPB) hist[i] = 0u;
    __syncthreads();

    unsigned pay[4];
    unsigned short bn[4];
    {
        const int lo = t * 4;
        if (lo + 4 <= cnt) {
            int s4[4], d4[4];
            load4(ei, is32, base + lo, s4);
            load4(ei, is32, (long long)E + base + lo, d4);
#pragma unroll
            for (int k = 0; k < 4; ++k) {
                pay[k] = ((unsigned)(d4[k] & 63) << 16) | (unsigned)s4[k];
                bn[k]  = (unsigned short)((unsigned)d4[k] >> 6);
                atomicAdd(&hist[bn[k]], 1u);
            }
        } else {
#pragma unroll
            for (int k = 0; k < 4; ++k) {
                int l = lo + k;
                if (l < cnt) {
                    int s_, d_;
                    if (is32) {
                        s_ = ((const int*)ei)[base + l];
                        d_ = ((const int*)ei)[(long long)E + base + l];
                    } else {
                        s_ = (int)((const long long*)ei)[base + l];
                        d_ = (int)((const long long*)ei)[(long long)E + base + l];
                    }
                    pay[k] = ((unsigned)(d_ & 63) << 16) | (unsigned)s_;
                    bn[k]  = (unsigned short)((unsigned)d_ >> 6);
                    atomicAdd(&hist[bn[k]], 1u);
                } else {
                    bn[k] = 0xFFFFu;  // invalid sentinel
                }
            }
        }
    }
    __syncthreads();

    // exclusive prefix over nbins (2 bins per thread + 512-wide scan)
    unsigned s0 = 0;
#pragma unroll
    for (int k = 0; k < 2; ++k) { int bq = t * 2 + k; if (bq < nbins) s0 += hist[bq]; }
    partial[t] = s0;
    __syncthreads();
    for (int o = 1; o < STPB; o <<= 1) {
        unsigned v = (t >= o) ? partial[t - o] : 0u;
        __syncthreads();
        partial[t] += v;
        __syncthreads();
    }
    unsigned run = (t == 0) ? 0u : partial[t - 1];
#pragma unroll
    for (int k = 0; k < 2; ++k) {
        int bq = t * 2 + k;
        if (bq < nbins) { bstart[bq] = run; cur[bq] = run; run += hist[bq]; }
    }
    __syncthreads();

    // LDS scatter into bin order
#pragma unroll
    for (int i = 0; i < 4; ++i) {
        if (bn[i] != 0xFFFFu) {
            unsigned p = atomicAdd(&cur[bn[i]], 1u);
            sorted[p] = pay[i];
        }
    }
    __syncthreads();

    // coalesced arena dump + contiguous descriptor dump
    for (int i = t; i < cnt; i += STPB) arena[base + i] = sorted[i];
    for (int bq = t; bq < nbins; bq += STPB) {
        uint2 dd;
        dd.x = (unsigned)(base + bstart[bq]);
        dd.y = hist[bq];
        desc[(long long)blk * nbins + bq] = dd;
    }
}

// ---- build_ell: per-bin segment stitch (up to 512 segs) -> LDS ELL ------
__global__ __launch_bounds__(256) void build_ell(const uint2* __restrict__ desc,
                                                 const unsigned* __restrict__ arena,
                                                 unsigned* __restrict__ fc,
                                                 unsigned short* __restrict__ ell,
                                                 unsigned* __restrict__ ovf,
                                                 int* __restrict__ ovfList,
                                                 unsigned short* __restrict__ z,
                                                 int n, int nbins, int nblocks) {
    __shared__ unsigned segstart[MAXBLK];
    __shared__ unsigned segpre[MAXBLK];
    __shared__ unsigned pre[MAXBLK];
    __shared__ unsigned lcnt[MAXDEG];
    __shared__ __align__(16) unsigned short lell[MAXDEG * MAXDEG];  // 8 KB
    const int t   = threadIdx.x;
    const int bin = blockIdx.x;
    const int base = bin * MAXDEG;

    if (t < MAXDEG) lcnt[t] = 0u;

    unsigned len0 = 0, len1 = 0;
    if (t < nblocks) {
        uint2 dd = desc[(long long)t * nbins + bin];
        segstart[t] = dd.x;
        len0 = dd.y;
    }
    if (t + 256 < nblocks) {
        uint2 dd = desc[(long long)(t + 256) * nbins + bin];
        segstart[t + 256] = dd.x;
        len1 = dd.y;
    }
    pre[t] = len0;
    pre[t + 256] = len1;
    __syncthreads();
    // scan both 256-halves simultaneously, then offset the upper half
    for (int o = 1; o < 256; o <<= 1) {
        unsigned vA = (t >= o) ? pre[t - o] : 0u;
        unsigned vB = (t >= o) ? pre[256 + t - o] : 0u;
        __syncthreads();
        pre[t] += vA;
        pre[256 + t] += vB;
        __syncthreads();
    }
    const unsigned lowTot = pre[255];
    pre[256 + t] += lowTot;   // no thread writes pre[255] here
    __syncthreads();
    const unsigned total = pre[MAXBLK - 1];
    if (t < nblocks) segpre[t] = pre[t] - len0;
    if (t + 256 < nblocks) segpre[t + 256] = pre[256 + t] - len1;
    __syncthreads();

    for (unsigned j = t; j < total; j += 256) {
        // largest k with segpre[k] <= j (segpre nondecreasing)
        int lo = 0, hi = nblocks - 1;
        while (lo < hi) {
            int mid = (lo + hi + 1) >> 1;
            if (segpre[mid] <= j) lo = mid; else hi = mid - 1;
        }
        unsigned e  = arena[segstart[lo] + (j - segpre[lo])];
        unsigned dl = e >> 16;
        unsigned c  = atomicAdd(&lcnt[dl], 1u);
        if (c < MAXDEG) {
            lell[dl * MAXDEG + c] = (unsigned short)(e & 0xFFFFu);
        } else {  // deg > 64: exact deg kept in lcnt; extra edge via ovfList
            unsigned p = atomicAdd(ovf, 1u);
            if (p < OVFCAP) {
                ovfList[2 * p]     = (int)(e & 0xFFFFu);
                ovfList[2 * p + 1] = base + (int)dl;
            }
        }
    }
    __syncthreads();

    const int maxrow = (n - base < MAXDEG) ? (n - base) : MAXDEG;
    if (t < maxrow) fc[base + t] = lcnt[t];

    // coalesced ELL dump: maxrow rows x 128B (8 uint4 per row)
    const uint4* lp = (const uint4*)lell;
    uint4* gp = (uint4*)(ell + (long long)base * MAXDEG);
    for (int i = t; i < maxrow * 8; i += 256) gp[i] = lp[i];

    // scale z rows in place: z[row] *= rsqrt(1 + deg)
    uint4* zp = (uint4*)(z + (long long)base * 64);
    for (int i = t; i < maxrow * 8; i += 256) {
        int row = i >> 3;
        float dd = rsqrtf(1.0f + (float)lcnt[row]);
        uint4 v = zp[i];
        v.x = scale2(v.x, dd); v.y = scale2(v.y, dd);
        v.z = scale2(v.z, dd); v.w = scale2(v.w, dd);
        zp[i] = v;
    }
}

// ---- gather: 4 nodes per wave; lane owns 4 channels (uint2 8B loads) ----
// out = relu( dd * (z[node] + sum z[nbr]) + b )
__global__ __launch_bounds__(256) void gather_z(const unsigned short* __restrict__ ell,
                                                const unsigned* __restrict__ fc,
                                                const unsigned* __restrict__ ovf,
                                                const int* __restrict__ ovfList,
                                                const unsigned short* __restrict__ z,
                                                const float* __restrict__ b,
                                                float* __restrict__ out, int n) {
    const int wv   = (int)threadIdx.x >> 6;
    const int lane = threadIdx.x & 63;
    const int q    = lane >> 4;       // quarter -> which node of the four
    const int cp   = lane & 15;       // channel quad (4 bf16 = 1 uint2)
    const int node = (blockIdx.x * 4 + wv) * 4 + q;
    const bool valid = node < n;
    const int nodec = valid ? node : (n - 1);  // clamped for safe addressing

    const unsigned deg = valid ? fc[nodec] : 0u;
    const float dd = rsqrtf(1.0f + (float)deg);

    uint2 zs = *(const uint2*)(z + (unsigned)nodec * 64 + cp * 4);
    float acc0 = bf2f((unsigned short)(zs.x & 0xFFFFu));   // self-loop term
    float acc1 = bf2f((unsigned short)(zs.x >> 16));
    float acc2 = bf2f((unsigned short)(zs.y & 0xFFFFu));
    float acc3 = bf2f((unsigned short)(zs.y >> 16));

    unsigned m = deg < MAXDEG ? deg : MAXDEG;
    if (!valid) m = 0u;
    unsigned mm = m;
    {   // wave-uniform trip count: max over the 4 quarters
        unsigned o1 = (unsigned)__shfl_xor((int)mm, 16); mm = mm > o1 ? mm : o1;
        unsigned o2 = (unsigned)__shfl_xor((int)mm, 32); mm = mm > o2 ? mm : o2;
    }
    const unsigned mmax = mm;

    const uint4* prow = (const uint4*)(ell + (unsigned)nodec * MAXDEG);

    unsigned i = 0;
    for (; i + 8 <= mmax; i += 8) {
        uint4 rw = prow[i >> 3];      // per-quarter broadcast of 8 ids
        unsigned s[8];
        s[0] = rw.x & 0xFFFFu; s[1] = rw.x >> 16;
        s[2] = rw.y & 0xFFFFu; s[3] = rw.y >> 16;
        s[4] = rw.z & 0xFFFFu; s[5] = rw.z >> 16;
        s[6] = rw.w & 0xFFFFu; s[7] = rw.w >> 16;
        if (i + 8 <= m) {             // full batch for this quarter
            uint2 v[8];
#pragma unroll
            for (int k = 0; k < 8; ++k)
                v[k] = *(const uint2*)(z + s[k] * 64u + cp * 4);
#pragma unroll
            for (int k = 0; k < 8; ++k) {
                acc0 += bf2f((unsigned short)(v[k].x & 0xFFFFu));
                acc1 += bf2f((unsigned short)(v[k].x >> 16));
                acc2 += bf2f((unsigned short)(v[k].y & 0xFFFFu));
                acc3 += bf2f((unsigned short)(v[k].y >> 16));
            }
        } else {                      // partial batch (divergent tail)
#pragma unroll
            for (int k = 0; k < 8; ++k) {
                if (i + k < m) {
                    uint2 v = *(const uint2*)(z + s[k] * 64u + cp * 4);
                    acc0 += bf2f((unsigned short)(v.x & 0xFFFFu));
                    acc1 += bf2f((unsigned short)(v.x >> 16));
                    acc2 += bf2f((unsigned short)(v.y & 0xFFFFu));
                    acc3 += bf2f((unsigned short)(v.y >> 16));
                }
            }
        }
    }
    for (; i < mmax; ++i) {
        if (i < m) {
            unsigned s = ell[(unsigned)nodec * MAXDEG + i];
            uint2 v = *(const uint2*)(z + s * 64u + cp * 4);
            acc0 += bf2f((unsigned short)(v.x & 0xFFFFu));
            acc1 += bf2f((unsigned short)(v.x >> 16));
            acc2 += bf2f((unsigned short)(v.y & 0xFFFFu));
            acc3 += bf2f((unsigned short)(v.y >> 16));
        }
    }

    unsigned nov = *ovf;  // overflow edges: normally zero
    if (nov > 0) {
        nov = nov < OVFCAP ? nov : OVFCAP;
        for (unsigned j = 0; j < nov; ++j)
            if (valid && ovfList[2 * j + 1] == node) {
                uint2 v = *(const uint2*)(z + (unsigned)ovfList[2 * j] * 64u + cp * 4);
                acc0 += bf2f((unsigned short)(v.x & 0xFFFFu));
                acc1 += bf2f((unsigned short)(v.x >> 16));
                acc2 += bf2f((unsigned short)(v.y & 0xFFFFu));
                acc3 += bf2f((unsigned short)(v.y >> 16));
            }
    }

    if (valid) {
        float4 bb = *(const float4*)(b + cp * 4);
        float4 o;
        o.x = fmaxf(fmaf(dd, acc0, bb.x), 0.f);
        o.y = fmaxf(fmaf(dd, acc1, bb.y), 0.f);
        o.z = fmaxf(fmaf(dd, acc2, bb.z), 0.f);
        o.w = fmaxf(fmaf(dd, acc3, bb.w), 0.f);
        *(float4*)(out + (unsigned)node * 64 + cp * 4) = o;
    }
}

extern "C" void kernel_launch(void* const* d_in, const int* in_sizes, int n_in,
                              void* d_out, int out_size, void* d_ws, size_t ws_size,
                              hipStream_t stream) {
    const float* x  = (const float*)d_in[0];
    const void*  ei = d_in[1];
    const float* W  = (const float*)d_in[2];
    const float* b  = (const float*)d_in[3];
    float* out = (float*)d_out;

    const int n = in_sizes[0] / 64;   // 50000
    const int E = in_sizes[1] / 2;    // 800000
    const int nbins   = (n + MAXDEG - 1) / MAXDEG;  // 782
    const int nblocks = (E + EPB - 1) / EPB;        // 391
    const int gemmBlocks = (n + 63) / 64;           // 782

    // ws: z[n*64] u16 (6.4M) | ell[n*64] u16 (6.4M) | fc[n] u32 (0.2M) |
    //     ovf u32 | ovfList[2*OVFCAP] (64K) | arena[E] u32 (3.2M) |
    //     desc[nblocks*nbins] uint2 (2.45M)  => ~18.7MB (< proven 19.46MB)
    unsigned short* z       = (unsigned short*)d_ws;
    unsigned short* ell     = z + (long long)n * 64;
    unsigned*       fc      = (unsigned*)(ell + (long long)n * 64);
    unsigned*       ovf     = fc + n;
    int*            ovfList = (int*)(ovf + 1);
    unsigned*       arena   = (unsigned*)(ovfList + 2 * OVFCAP);
    uint2*          desc    = (uint2*)(arena + E);

    gemm_binsort<<<gemmBlocks + nblocks, STPB, 0, stream>>>(
        x, W, z, ovf, ei, arena, desc, E, nbins, nblocks, n, gemmBlocks);
    build_ell<<<nbins, TPB, 0, stream>>>(desc, arena, fc, ell, ovf, ovfList, z,
                                         n, nbins, nblocks);
    gather_z<<<(n + 15) / 16, TPB, 0, stream>>>(ell, fc, ovf, ovfList, z, b, out, n);
}

// Round 18
// 76.055 us; speedup vs baseline: 3.6061x; 1.0316x over previous
//
#include <hip/hip_runtime.h>

// GCNBlock: out = relu( D^-1/2 (A+I) D^-1/2 (x@W) + b )
// N=50000, E=800000, D=64, fp32.
// R18 (= R17 + compile fix): __builtin_nontemporal_store needs a NATIVE
// vector type -> ext_vector_type(4) float alias instead of HIP float4.
// Changes vs R16: build_ell LDS j->segment LUT (2 LDS reads/edge instead of
// 9-step binary search); gather 8 nodes/wave (lane owns 8 channels, uint4
// 16B z loads); nontemporal out stores. Rest frozen.

#define TPB 256
#define STPB 512      // fused kernel block size
#define MAXDEG 64
#define OVFCAP 8192
#define EPB 2048      // edges per binsort block
#define MAXBIN 1024   // supports n <= 65536
#define MAXBLK 512    // supports E <= 1M (512*2048)
#define LUTSZ 2048    // j->segment LUT entries (bin mean 1024, 32 sigma)

typedef float fvec4 __attribute__((ext_vector_type(4)));  // nontemporal-safe

// ---- per-wave edge dtype detection --------------------------------------
// int64 little-endian with values <2^31 => every odd 32-bit word is 0.
__device__ __forceinline__ int edges_are_i32(const unsigned* __restrict__ w) {
    int lane = threadIdx.x & 63;
    unsigned v = w[1 + 2 * lane];
    return __ballot(v != 0u) != 0ull;
}

__device__ __forceinline__ unsigned short f2bf(float f) {  // RNE to bf16
    unsigned u = __float_as_uint(f);
    u += 0x7FFFu + ((u >> 16) & 1u);
    return (unsigned short)(u >> 16);
}
__device__ __forceinline__ float bf2f(unsigned short h) {
    return __uint_as_float(((unsigned)h) << 16);
}
__device__ __forceinline__ unsigned scale2(unsigned v, float dd) {  // 2 bf16
    unsigned lo = (unsigned)f2bf(dd * bf2f((unsigned short)(v & 0xFFFFu)));
    unsigned hi = (unsigned)f2bf(dd * bf2f((unsigned short)(v >> 16)));
    return lo | (hi << 16);
}

__device__ __forceinline__ void load4(const void* ei, int is32, long long base, int* v) {
    if (is32) {
        int4 a = *(const int4*)((const int*)ei + base);
        v[0] = a.x; v[1] = a.y; v[2] = a.z; v[3] = a.w;
    } else {
        longlong4 a = *(const longlong4*)((const long long*)ei + base);
        v[0] = (int)a.x; v[1] = (int)a.y; v[2] = (int)a.z; v[3] = (int)a.w;
    }
}

// ---- fused: gemm z0=bf16(x@W) (blocks < gemmBlocks) || binsort (rest) ---
__global__ __launch_bounds__(512) void gemm_binsort(
        const float* __restrict__ x, const float* __restrict__ W,
        unsigned short* __restrict__ z0, unsigned* __restrict__ ovf,
        const void* __restrict__ ei, unsigned* __restrict__ arena,
        uint2* __restrict__ desc, int E, int nbins, int nblocks,
        int n, int gemmBlocks) {
    __shared__ __align__(16) unsigned char smem[22528];  // max(16KB, 22KB)
    const int t = threadIdx.x;

    if ((int)blockIdx.x < gemmBlocks) {
        // ---- gemm: LDS-staged W; lane = column; 8 waves x 8 rows ----
        if (blockIdx.x == 0 && t == 0) *ovf = 0u;
        float* lw = (float*)smem;  // W[k*64+c], 16 KB
#pragma unroll
        for (int i = 0; i < 8; ++i) lw[i * 512 + t] = W[i * 512 + t];
        __syncthreads();

        const int lane = t & 63;
        const int wv   = t >> 6;                  // 0..7
        const int row0 = blockIdx.x * 64 + wv * 8;
        if (row0 >= n) return;  // wave-uniform
        const int nr = (n - row0 >= 8) ? 8 : (n - row0);

        float acc[8] = {0.f, 0.f, 0.f, 0.f, 0.f, 0.f, 0.f, 0.f};
#pragma unroll
        for (int k0 = 0; k0 < 16; ++k0) {
            const float w0 = lw[(4 * k0 + 0) * 64 + lane];
            const float w1 = lw[(4 * k0 + 1) * 64 + lane];
            const float w2 = lw[(4 * k0 + 2) * 64 + lane];
            const float w3 = lw[(4 * k0 + 3) * 64 + lane];
#pragma unroll
            for (int r = 0; r < 8; ++r) {
                if (r < nr) {
                    float4 xv = *(const float4*)(x + (long long)(row0 + r) * 64 + 4 * k0);
                    acc[r] = fmaf(xv.w, w3, fmaf(xv.z, w2, fmaf(xv.y, w1,
                             fmaf(xv.x, w0, acc[r]))));
                }
            }
        }
#pragma unroll
        for (int r = 0; r < 8; ++r)
            if (r < nr) z0[(long long)(row0 + r) * 64 + lane] = f2bf(acc[r]);
        return;
    }

    // ---- binsort: LDS counting sort of 2048 edges by dst>>6 ----
    unsigned* hist    = (unsigned*)smem;            // [MAXBIN]
    unsigned* bstart  = hist + MAXBIN;              // [MAXBIN]
    unsigned* cur     = bstart + MAXBIN;            // [MAXBIN]
    unsigned* sorted  = cur + MAXBIN;               // [EPB]
    unsigned* partial = sorted + EPB;               // [STPB]
    const int blk = (int)blockIdx.x - gemmBlocks;
    const long long base = (long long)blk * EPB;
    const int cnt = (int)((E - base < EPB) ? (E - base) : EPB);
    const int is32 = edges_are_i32((const unsigned*)ei);

    for (int i = t; i < nbins; i += STPB) hist[i] = 0u;
    __syncthreads();

    unsigned pay[4];
    unsigned short bn[4];
    {
        const int lo = t * 4;
        if (lo + 4 <= cnt) {
            int s4[4], d4[4];
            load4(ei, is32, base + lo, s4);
            load4(ei, is32, (long long)E + base + lo, d4);
#pragma unroll
            for (int k = 0; k < 4; ++k) {
                pay[k] = ((unsigned)(d4[k] & 63) << 16) | (unsigned)s4[k];
                bn[k]  = (unsigned short)((unsigned)d4[k] >> 6);
                atomicAdd(&hist[bn[k]], 1u);
            }
        } else {
#pragma unroll
            for (int k = 0; k < 4; ++k) {
                int l = lo + k;
                if (l < cnt) {
                    int s_, d_;
                    if (is32) {
                        s_ = ((const int*)ei)[base + l];
                        d_ = ((const int*)ei)[(long long)E + base + l];
                    } else {
                        s_ = (int)((const long long*)ei)[base + l];
                        d_ = (int)((const long long*)ei)[(long long)E + base + l];
                    }
                    pay[k] = ((unsigned)(d_ & 63) << 16) | (unsigned)s_;
                    bn[k]  = (unsigned short)((unsigned)d_ >> 6);
                    atomicAdd(&hist[bn[k]], 1u);
                } else {
                    bn[k] = 0xFFFFu;  // invalid sentinel
                }
            }
        }
    }
    __syncthreads();

    // exclusive prefix over nbins (2 bins per thread + 512-wide scan)
    unsigned s0 = 0;
#pragma unroll
    for (int k = 0; k < 2; ++k) { int bq = t * 2 + k; if (bq < nbins) s0 += hist[bq]; }
    partial[t] = s0;
    __syncthreads();
    for (int o = 1; o < STPB; o <<= 1) {
        unsigned v = (t >= o) ? partial[t - o] : 0u;
        __syncthreads();
        partial[t] += v;
        __syncthreads();
    }
    unsigned run = (t == 0) ? 0u : partial[t - 1];
#pragma unroll
    for (int k = 0; k < 2; ++k) {
        int bq = t * 2 + k;
        if (bq < nbins) { bstart[bq] = run; cur[bq] = run; run += hist[bq]; }
    }
    __syncthreads();

    // LDS scatter into bin order
#pragma unroll
    for (int i = 0; i < 4; ++i) {
        if (bn[i] != 0xFFFFu) {
            unsigned p = atomicAdd(&cur[bn[i]], 1u);
            sorted[p] = pay[i];
        }
    }
    __syncthreads();

    // coalesced arena dump + contiguous descriptor dump
    for (int i = t; i < cnt; i += STPB) arena[base + i] = sorted[i];
    for (int bq = t; bq < nbins; bq += STPB) {
        uint2 dd;
        dd.x = (unsigned)(base + bstart[bq]);
        dd.y = hist[bq];
        desc[(long long)blk * nbins + bq] = dd;
    }
}

// ---- build_ell: per-bin segment stitch -> LDS ELL -> coalesced dump -----
// j->segment via LDS LUT (2 LDS reads/edge; binary-search fallback j>=LUTSZ).
__global__ __launch_bounds__(256) void build_ell(const uint2* __restrict__ desc,
                                                 const unsigned* __restrict__ arena,
                                                 unsigned* __restrict__ fc,
                                                 unsigned short* __restrict__ ell,
                                                 unsigned* __restrict__ ovf,
                                                 int* __restrict__ ovfList,
                                                 unsigned short* __restrict__ z,
                                                 int n, int nbins, int nblocks) {
    __shared__ unsigned segstart[MAXBLK];
    __shared__ unsigned segpre[MAXBLK];
    __shared__ unsigned pre[MAXBLK];
    __shared__ unsigned lcnt[MAXDEG];
    __shared__ unsigned short lut[LUTSZ];                           // 4 KB
    __shared__ __align__(16) unsigned short lell[MAXDEG * MAXDEG];  // 8 KB
    const int t   = threadIdx.x;
    const int bin = blockIdx.x;
    const int base = bin * MAXDEG;

    if (t < MAXDEG) lcnt[t] = 0u;

    unsigned len0 = 0, len1 = 0;
    if (t < nblocks) {
        uint2 dd = desc[(long long)t * nbins + bin];
        segstart[t] = dd.x;
        len0 = dd.y;
    }
    if (t + 256 < nblocks) {
        uint2 dd = desc[(long long)(t + 256) * nbins + bin];
        segstart[t + 256] = dd.x;
        len1 = dd.y;
    }
    pre[t] = len0;
    pre[t + 256] = len1;
    __syncthreads();
    // scan both 256-halves simultaneously, then offset the upper half
    for (int o = 1; o < 256; o <<= 1) {
        unsigned vA = (t >= o) ? pre[t - o] : 0u;
        unsigned vB = (t >= o) ? pre[256 + t - o] : 0u;
        __syncthreads();
        pre[t] += vA;
        pre[256 + t] += vB;
        __syncthreads();
    }
    const unsigned lowTot = pre[255];
    pre[256 + t] += lowTot;   // no thread writes pre[255] here
    __syncthreads();
    const unsigned total = pre[MAXBLK - 1];
    unsigned sp0 = 0, sp1 = 0;
    if (t < nblocks) { sp0 = pre[t] - len0; segpre[t] = sp0; }
    if (t + 256 < nblocks) { sp1 = pre[256 + t] - len1; segpre[t + 256] = sp1; }
    __syncthreads();

    // fill j->segment LUT (each thread writes its own segments' spans)
    for (unsigned k = 0; k < len0 && sp0 + k < LUTSZ; ++k)
        lut[sp0 + k] = (unsigned short)t;
    for (unsigned k = 0; k < len1 && sp1 + k < LUTSZ; ++k)
        lut[sp1 + k] = (unsigned short)(t + 256);
    __syncthreads();

    for (unsigned j = t; j < total; j += 256) {
        int lo;
        if (j < LUTSZ) {
            lo = (int)lut[j];
        } else {  // fallback: largest k with segpre[k] <= j
            int l = 0, hi = nblocks - 1;
            while (l < hi) {
                int mid = (l + hi + 1) >> 1;
                if (segpre[mid] <= j) l = mid; else hi = mid - 1;
            }
            lo = l;
        }
        unsigned e  = arena[segstart[lo] + (j - segpre[lo])];
        unsigned dl = e >> 16;
        unsigned c  = atomicAdd(&lcnt[dl], 1u);
        if (c < MAXDEG) {
            lell[dl * MAXDEG + c] = (unsigned short)(e & 0xFFFFu);
        } else {  // deg > 64: exact deg kept in lcnt; extra edge via ovfList
            unsigned p = atomicAdd(ovf, 1u);
            if (p < OVFCAP) {
                ovfList[2 * p]     = (int)(e & 0xFFFFu);
                ovfList[2 * p + 1] = base + (int)dl;
            }
        }
    }
    __syncthreads();

    const int maxrow = (n - base < MAXDEG) ? (n - base) : MAXDEG;
    if (t < maxrow) fc[base + t] = lcnt[t];

    // coalesced ELL dump: maxrow rows x 128B (8 uint4 per row)
    const uint4* lp = (const uint4*)lell;
    uint4* gp = (uint4*)(ell + (long long)base * MAXDEG);
    for (int i = t; i < maxrow * 8; i += 256) gp[i] = lp[i];

    // scale z rows in place: z[row] *= rsqrt(1 + deg)
    uint4* zp = (uint4*)(z + (long long)base * 64);
    for (int i = t; i < maxrow * 8; i += 256) {
        int row = i >> 3;
        float dd = rsqrtf(1.0f + (float)lcnt[row]);
        uint4 v = zp[i];
        v.x = scale2(v.x, dd); v.y = scale2(v.y, dd);
        v.z = scale2(v.z, dd); v.w = scale2(v.w, dd);
        zp[i] = v;
    }
}

// ---- gather: 8 nodes/wave; lane owns 8 channels (uint4 16B loads) -------
// out = relu( dd * (z[node] + sum z[nbr]) + b ), nontemporal out stores.
__global__ __launch_bounds__(256) void gather_z(const unsigned short* __restrict__ ell,
                                                const unsigned* __restrict__ fc,
                                                const unsigned* __restrict__ ovf,
                                                const int* __restrict__ ovfList,
                                                const unsigned short* __restrict__ z,
                                                const float* __restrict__ b,
                                                float* __restrict__ out, int n) {
    const int wv   = (int)threadIdx.x >> 6;
    const int lane = threadIdx.x & 63;
    const int o    = lane >> 3;       // octant -> which node of the eight
    const int cp   = lane & 7;        // channel octet (8 bf16 = 1 uint4)
    const int node = (blockIdx.x * 4 + wv) * 8 + o;
    const bool valid = node < n;
    const int nodec = valid ? node : (n - 1);  // clamped for safe addressing

    const unsigned deg = valid ? fc[nodec] : 0u;
    const float dd = rsqrtf(1.0f + (float)deg);

    uint4 zs = *(const uint4*)(z + (unsigned)nodec * 64 + cp * 8);
    float a0 = bf2f((unsigned short)(zs.x & 0xFFFFu));   // self-loop term
    float a1 = bf2f((unsigned short)(zs.x >> 16));
    float a2 = bf2f((unsigned short)(zs.y & 0xFFFFu));
    float a3 = bf2f((unsigned short)(zs.y >> 16));
    float a4 = bf2f((unsigned short)(zs.z & 0xFFFFu));
    float a5 = bf2f((unsigned short)(zs.z >> 16));
    float a6 = bf2f((unsigned short)(zs.w & 0xFFFFu));
    float a7 = bf2f((unsigned short)(zs.w >> 16));

    unsigned m = deg < MAXDEG ? deg : MAXDEG;
    if (!valid) m = 0u;
    unsigned mm = m;
    {   // wave-uniform trip count: max over the 8 octants
        unsigned q1 = (unsigned)__shfl_xor((int)mm, 8);  mm = mm > q1 ? mm : q1;
        unsigned q2 = (unsigned)__shfl_xor((int)mm, 16); mm = mm > q2 ? mm : q2;
        unsigned q3 = (unsigned)__shfl_xor((int)mm, 32); mm = mm > q3 ? mm : q3;
    }
    const unsigned mmax = mm;

    const uint4* prow = (const uint4*)(ell + (unsigned)nodec * MAXDEG);

    unsigned i = 0;
    for (; i + 8 <= mmax; i += 8) {
        uint4 rw = prow[i >> 3];      // per-octant broadcast of 8 ids
        unsigned s[8];
        s[0] = rw.x & 0xFFFFu; s[1] = rw.x >> 16;
        s[2] = rw.y & 0xFFFFu; s[3] = rw.y >> 16;
        s[4] = rw.z & 0xFFFFu; s[5] = rw.z >> 16;
        s[6] = rw.w & 0xFFFFu; s[7] = rw.w >> 16;
        if (i + 8 <= m) {             // full batch for this octant
            uint4 v[8];
#pragma unroll
            for (int k = 0; k < 8; ++k)
                v[k] = *(const uint4*)(z + s[k] * 64u + cp * 8);
#pragma unroll
            for (int k = 0; k < 8; ++k) {
                a0 += bf2f((unsigned short)(v[k].x & 0xFFFFu));
                a1 += bf2f((unsigned short)(v[k].x >> 16));
                a2 += bf2f((unsigned short)(v[k].y & 0xFFFFu));
                a3 += bf2f((unsigned short)(v[k].y >> 16));
                a4 += bf2f((unsigned short)(v[k].z & 0xFFFFu));
                a5 += bf2f((unsigned short)(v[k].z >> 16));
                a6 += bf2f((unsigned short)(v[k].w & 0xFFFFu));
                a7 += bf2f((unsigned short)(v[k].w >> 16));
            }
        } else {                      // partial batch (divergent tail)
#pragma unroll
            for (int k = 0; k < 8; ++k) {
                if (i + k < m) {
                    uint4 v = *(const uint4*)(z + s[k] * 64u + cp * 8);
                    a0 += bf2f((unsigned short)(v.x & 0xFFFFu));
                    a1 += bf2f((unsigned short)(v.x >> 16));
                    a2 += bf2f((unsigned short)(v.y & 0xFFFFu));
                    a3 += bf2f((unsigned short)(v.y >> 16));
                    a4 += bf2f((unsigned short)(v.z & 0xFFFFu));
                    a5 += bf2f((unsigned short)(v.z >> 16));
                    a6 += bf2f((unsigned short)(v.w & 0xFFFFu));
                    a7 += bf2f((unsigned short)(v.w >> 16));
                }
            }
        }
    }
    for (; i < mmax; ++i) {
        if (i < m) {
            unsigned s = ell[(unsigned)nodec * MAXDEG + i];
            uint4 v = *(const uint4*)(z + s * 64u + cp * 8);
            a0 += bf2f((unsigned short)(v.x & 0xFFFFu));
            a1 += bf2f((unsigned short)(v.x >> 16));
            a2 += bf2f((unsigned short)(v.y & 0xFFFFu));
            a3 += bf2f((unsigned short)(v.y >> 16));
            a4 += bf2f((unsigned short)(v.z & 0xFFFFu));
            a5 += bf2f((unsigned short)(v.z >> 16));
            a6 += bf2f((unsigned short)(v.w & 0xFFFFu));
            a7 += bf2f((unsigned short)(v.w >> 16));
        }
    }

    unsigned nov = *ovf;  // overflow edges: normally zero
    if (nov > 0) {
        nov = nov < OVFCAP ? nov : OVFCAP;
        for (unsigned j = 0; j < nov; ++j)
            if (valid && ovfList[2 * j + 1] == node) {
                uint4 v = *(const uint4*)(z + (unsigned)ovfList[2 * j] * 64u + cp * 8);
                a0 += bf2f((unsigned short)(v.x & 0xFFFFu));
                a1 += bf2f((unsigned short)(v.x >> 16));
                a2 += bf2f((unsigned short)(v.y & 0xFFFFu));
                a3 += bf2f((unsigned short)(v.y >> 16));
                a4 += bf2f((unsigned short)(v.z & 0xFFFFu));
                a5 += bf2f((unsigned short)(v.z >> 16));
                a6 += bf2f((unsigned short)(v.w & 0xFFFFu));
                a7 += bf2f((unsigned short)(v.w >> 16));
            }
    }

    if (valid) {
        float4 b0 = *(const float4*)(b + cp * 8);
        float4 b1 = *(const float4*)(b + cp * 8 + 4);
        fvec4 o0, o1;
        o0.x = fmaxf(fmaf(dd, a0, b0.x), 0.f);
        o0.y = fmaxf(fmaf(dd, a1, b0.y), 0.f);
        o0.z = fmaxf(fmaf(dd, a2, b0.z), 0.f);
        o0.w = fmaxf(fmaf(dd, a3, b0.w), 0.f);
        o1.x = fmaxf(fmaf(dd, a4, b1.x), 0.f);
        o1.y = fmaxf(fmaf(dd, a5, b1.y), 0.f);
        o1.z = fmaxf(fmaf(dd, a6, b1.z), 0.f);
        o1.w = fmaxf(fmaf(dd, a7, b1.w), 0.f);
        __builtin_nontemporal_store(o0, (fvec4*)(out + (unsigned)node * 64 + cp * 8));
        __builtin_nontemporal_store(o1, (fvec4*)(out + (unsigned)node * 64 + cp * 8 + 4));
    }
}

extern "C" void kernel_launch(void* const* d_in, const int* in_sizes, int n_in,
                              void* d_out, int out_size, void* d_ws, size_t ws_size,
                              hipStream_t stream) {
    const float* x  = (const float*)d_in[0];
    const void*  ei = d_in[1];
    const float* W  = (const float*)d_in[2];
    const float* b  = (const float*)d_in[3];
    float* out = (float*)d_out;

    const int n = in_sizes[0] / 64;   // 50000
    const int E = in_sizes[1] / 2;    // 800000
    const int nbins   = (n + MAXDEG - 1) / MAXDEG;  // 782
    const int nblocks = (E + EPB - 1) / EPB;        // 391
    const int gemmBlocks = (n + 63) / 64;           // 782

    // ws: z[n*64] u16 (6.4M) | ell[n*64] u16 (6.4M) | fc[n] u32 (0.2M) |
    //     ovf u32 | ovfList[2*OVFCAP] (64K) | arena[E] u32 (3.2M) |
    //     desc[nblocks*nbins] uint2 (2.45M)  => ~18.7MB (< proven 19.46MB)
    unsigned short* z       = (unsigned short*)d_ws;
    unsigned short* ell     = z + (long long)n * 64;
    unsigned*       fc      = (unsigned*)(ell + (long long)n * 64);
    unsigned*       ovf     = fc + n;
    int*            ovfList = (int*)(ovf + 1);
    unsigned*       arena   = (unsigned*)(ovfList + 2 * OVFCAP);
    uint2*          desc    = (uint2*)(arena + E);

    gemm_binsort<<<gemmBlocks + nblocks, STPB, 0, stream>>>(
        x, W, z, ovf, ei, arena, desc, E, nbins, nblocks, n, gemmBlocks);
    build_ell<<<nbins, TPB, 0, stream>>>(desc, arena, fc, ell, ovf, ovfList, z,
                                         n, nbins, nblocks);
    gather_z<<<(n + 31) / 32, TPB, 0, stream>>>(ell, fc, ovf, ovfList, z, b, out, n);
}